// Round 1
// baseline (694.133 us; speedup 1.0000x reference)
//
#include <hip/hip_runtime.h>
#include <hip/hip_bf16.h>

// DeBERTa layer: B=16,S=512,H=1024,NH=8,HD=128,FF=3072.
// R9: dense GEMMs (QKV/Wo/Wi/Wf) moved to a 256x256 8-phase schedule
// (T2 LDS XOR-swizzle + T3/T4 counted-vmcnt global_load_lds pipeline +
// T5 setprio). Old 128x128 kernel kept for batched QK^T / PV.
#define BB  16
#define SS  512
#define HH  1024
#define NHH 8
#define HDD 128
#define FFF 3072
#define TT  (BB * SS)   // 8192 tokens

typedef __hip_bfloat16 bf16;
typedef short s8v __attribute__((ext_vector_type(8)));   // 8 bf16 bits (4 VGPRs)
typedef float f4v __attribute__((ext_vector_type(4)));   // 4 f32 acc

__device__ __forceinline__ float bf2f(bf16 v) { return __bfloat162float(v); }
__device__ __forceinline__ bf16 f2bf(float f) { return __float2bfloat16(f); }
__device__ __forceinline__ float us2f(unsigned short u) {
  union { unsigned int i; float f; } c; c.i = (unsigned int)u << 16; return c.f;
}

// ---------------- Embedding LayerNorm (f32 in -> bf16 out) ----------------------
__global__ void embed_ln_kernel(const float* __restrict__ x, const float* __restrict__ pos,
                                const float* __restrict__ g, const float* __restrict__ bta,
                                bf16* __restrict__ h) {
  int t = blockIdx.x;
  int s = t & (SS - 1);
  int tid = threadIdx.x;
  const float* xr = x + (size_t)t * HH;
  const float* pr = pos + (size_t)s * HH;
  float vals[4];
  float sum = 0.f;
#pragma unroll
  for (int i = 0; i < 4; i++) {
    int c = tid + i * 256;
    vals[i] = xr[c] + pr[c];
    sum += vals[i];
  }
  __shared__ float red[4];
#pragma unroll
  for (int off = 32; off > 0; off >>= 1) sum += __shfl_down(sum, off, 64);
  if ((tid & 63) == 0) red[tid >> 6] = sum;
  __syncthreads();
  float mean = (red[0] + red[1] + red[2] + red[3]) * (1.f / HH);
  float vsum = 0.f;
#pragma unroll
  for (int i = 0; i < 4; i++) { float d = vals[i] - mean; vsum += d * d; }
  __syncthreads();
#pragma unroll
  for (int off = 32; off > 0; off >>= 1) vsum += __shfl_down(vsum, off, 64);
  if ((tid & 63) == 0) red[tid >> 6] = vsum;
  __syncthreads();
  float rstd = rsqrtf((red[0] + red[1] + red[2] + red[3]) * (1.f / HH) + 1e-7f);
  bf16* hr = h + (size_t)t * HH;
#pragma unroll
  for (int i = 0; i < 4; i++) {
    int c = tid + i * 256;
    hr[c] = f2bf((vals[i] - mean) * rstd * g[c] + bta[c]);
  }
}

// ------- a(bf16)+res(bf16) -> LN -> out (OUT_F32 ? float : bf16) ---------------
template <int OUT_F32>
__global__ void add_ln_kernel(const bf16* __restrict__ a, const bf16* __restrict__ res,
                              const float* __restrict__ g, const float* __restrict__ bta,
                              void* __restrict__ outv) {
  int t = blockIdx.x;
  int tid = threadIdx.x;
  const bf16* ar = a + (size_t)t * HH;
  const bf16* rr = res + (size_t)t * HH;
  float vals[4];
  float sum = 0.f;
#pragma unroll
  for (int i = 0; i < 4; i++) {
    int c = tid + i * 256;
    vals[i] = bf2f(ar[c]) + bf2f(rr[c]);
    sum += vals[i];
  }
  __shared__ float red[4];
#pragma unroll
  for (int off = 32; off > 0; off >>= 1) sum += __shfl_down(sum, off, 64);
  if ((tid & 63) == 0) red[tid >> 6] = sum;
  __syncthreads();
  float mean = (red[0] + red[1] + red[2] + red[3]) * (1.f / HH);
  float vsum = 0.f;
#pragma unroll
  for (int i = 0; i < 4; i++) { float d = vals[i] - mean; vsum += d * d; }
  __syncthreads();
#pragma unroll
  for (int off = 32; off > 0; off >>= 1) vsum += __shfl_down(vsum, off, 64);
  if ((tid & 63) == 0) red[tid >> 6] = vsum;
  __syncthreads();
  float rstd = rsqrtf((red[0] + red[1] + red[2] + red[3]) * (1.f / HH) + 1e-7f);
#pragma unroll
  for (int i = 0; i < 4; i++) {
    int c = tid + i * 256;
    float o = (vals[i] - mean) * rstd * g[c] + bta[c];
    if (OUT_F32)
      ((float*)outv)[(size_t)t * HH + c] = o;
    else
      ((bf16*)outv)[(size_t)t * HH + c] = f2bf(o);
  }
}

// ---- weight convert+transpose: W[K,N] f32 -> Wt[N,K] bf16 (K fixed per call) --
__global__ void convert_w_kernel(const float* __restrict__ W, bf16* __restrict__ Wt,
                                 int K, int N) {
  __shared__ float tile[32][33];
  int n0 = blockIdx.x * 32, k0 = blockIdx.y * 32;
#pragma unroll
  for (int it = 0; it < 4; it++) {
    int idx = threadIdx.x + it * 256;
    int ty = idx >> 5, tx = idx & 31;
    tile[ty][tx] = W[(size_t)(k0 + ty) * N + n0 + tx];
  }
  __syncthreads();
#pragma unroll
  for (int it = 0; it < 4; it++) {
    int idx = threadIdx.x + it * 256;
    int ty = idx >> 5, tx = idx & 31;
    Wt[(size_t)(n0 + ty) * K + k0 + tx] = f2bf(tile[tx][ty]);
  }
}

// ---- concat qkv bias: [qbias | 0 | vbias] (f32) -------------------------------
__global__ void build_qkv_bias_kernel(const float* __restrict__ qb,
                                      const float* __restrict__ vb,
                                      float* __restrict__ o) {
  int i = blockIdx.x * 256 + threadIdx.x;  // 0..3071
  float v = 0.f;
  if (i < HH) v = qb[i];
  else if (i >= 2 * HH) v = vb[i - 2 * HH];
  o[i] = v;
}

// ---- V transpose per head: qkv v-cols -> vt[b,h,dim,key] (bf16) ---------------
__global__ void transpose_v_kernel(const bf16* __restrict__ v, bf16* __restrict__ vt) {
  __shared__ unsigned short tile[32][33];
  int bh = blockIdx.z;
  int s0 = blockIdx.x * 32, d0 = blockIdx.y * 32;
  int b = bh >> 3, hd = bh & 7;
  const unsigned short* vp = (const unsigned short*)v + ((size_t)b * SS) * (3 * HH) + hd * HDD;
  unsigned short* vtp = (unsigned short*)vt + (size_t)bh * HDD * SS;
#pragma unroll
  for (int it = 0; it < 4; it++) {
    int idx = threadIdx.x + it * 256;
    int ty = idx >> 5, tx = idx & 31;
    tile[ty][tx] = vp[(size_t)(s0 + ty) * (3 * HH) + d0 + tx];
  }
  __syncthreads();
#pragma unroll
  for (int it = 0; it < 4; it++) {
    int idx = threadIdx.x + it * 256;
    int ty = idx >> 5, tx = idx & 31;
    vtp[(size_t)(d0 + ty) * SS + s0 + tx] = tile[tx][ty];
  }
}

// ---- 128x128 MFMA GEMM (kept for batched QK^T / PV) ---------------------------
template <int GELU>
__global__ __launch_bounds__(256)
void mfma_gemm_kernel(const bf16* __restrict__ A, int lda, long long sAb, long long sAh,
                      const bf16* __restrict__ Bt, int ldb, long long sBb, long long sBh,
                      const float* __restrict__ bias,
                      bf16* __restrict__ C, int ldc, long long sCb, long long sCh,
                      int M, int N, int K, float scale) {
  __shared__ unsigned short Als[128 * 40];
  __shared__ unsigned short Bls[128 * 40];
  int tid = threadIdx.x;
  int lane = tid & 63, wave = tid >> 6;
  int l15 = lane & 15, quad = lane >> 4;
  int wm = wave & 1, wn = wave >> 1;
  int m0 = blockIdx.y * 128, n0 = blockIdx.x * 128;
  int zb = blockIdx.z >> 3, zh = blockIdx.z & 7;
  const bf16* Ab = A + zb * sAb + zh * sAh;
  const bf16* Bb = Bt + zb * sBb + zh * sBh;
  bf16* Cb = C + zb * sCb + zh * sCh;
  f4v acc[4][4];
#pragma unroll
  for (int i = 0; i < 4; i++)
#pragma unroll
    for (int j = 0; j < 4; j++) acc[i][j] = (f4v){0.f, 0.f, 0.f, 0.f};
  int r0 = tid >> 2;
  int q8 = (tid & 3) * 8;
  const bf16* Ap0 = Ab + (size_t)(m0 + r0) * lda + q8;
  const bf16* Ap1 = Ab + (size_t)(m0 + r0 + 64) * lda + q8;
  const bf16* Bp0 = Bb + (size_t)(n0 + r0) * ldb + q8;
  const bf16* Bp1 = Bb + (size_t)(n0 + r0 + 64) * ldb + q8;
  uint4 a0 = *(const uint4*)(Ap0);
  uint4 a1 = *(const uint4*)(Ap1);
  uint4 b0 = *(const uint4*)(Bp0);
  uint4 b1 = *(const uint4*)(Bp1);
  for (int k0 = 0; k0 < K; k0 += 32) {
    *(uint4*)&Als[r0 * 40 + q8] = a0;
    *(uint4*)&Als[(r0 + 64) * 40 + q8] = a1;
    *(uint4*)&Bls[r0 * 40 + q8] = b0;
    *(uint4*)&Bls[(r0 + 64) * 40 + q8] = b1;
    __syncthreads();
    int kn = k0 + 32;
    if (kn < K) {
      a0 = *(const uint4*)(Ap0 + kn);
      a1 = *(const uint4*)(Ap1 + kn);
      b0 = *(const uint4*)(Bp0 + kn);
      b1 = *(const uint4*)(Bp1 + kn);
    }
    s8v af[4], bfr[4];
#pragma unroll
    for (int i = 0; i < 4; i++)
      af[i] = *(const s8v*)&Als[(wm * 64 + i * 16 + l15) * 40 + quad * 8];
#pragma unroll
    for (int j = 0; j < 4; j++)
      bfr[j] = *(const s8v*)&Bls[(wn * 64 + j * 16 + l15) * 40 + quad * 8];
#pragma unroll
    for (int i = 0; i < 4; i++)
#pragma unroll
      for (int j = 0; j < 4; j++)
        acc[i][j] = __builtin_amdgcn_mfma_f32_16x16x32_bf16(af[i], bfr[j], acc[i][j], 0, 0, 0);
    __syncthreads();
  }
#pragma unroll
  for (int i = 0; i < 4; i++) {
#pragma unroll
    for (int j = 0; j < 4; j++) {
      int n = n0 + wn * 64 + j * 16 + l15;
      float bval = bias ? bias[n] : 0.f;
#pragma unroll
      for (int r = 0; r < 4; r++) {
        int m = m0 + wm * 64 + i * 16 + quad * 4 + r;
        float v = (acc[i][j][r] + bval) * scale;
        if (GELU) v = 0.5f * v * (1.f + erff(v * 0.70710678118654752f));
        Cb[(size_t)m * ldc + n] = f2bf(v);
      }
    }
  }
}

// =================== 256x256 8-phase dense GEMM ================================
// C[M,N](bf16) = act(A[M,K] @ Bt[N,K]^T + bias).  512 thr = 8 waves (2M x 4N),
// per-wave 128x64 output (acc[8][4] f4v). BK=64, LDS 128 KiB:
//   A: bytes [0,65536)      = 2 bufs x 256 rows x 64 cols bf16
//   B: bytes [65536,131072) = same (rows = n)
// Storage swizzle: 16B chunk c of row r stored at chunk c ^ (r&7)  -> ds_read_b128
// of 16 consecutive rows at one k-chunk spreads over all 32 banks (conflict-free).
// global_load_lds writes LDS linearly (base+lane*16), so the swizzle is applied by
// permuting the per-lane GLOBAL source column: col = 8*((tid&7)^((tid>>3)&7)).
// Pipeline: tiles t(even)->buf0, t+1->buf1. Reads of tile t happen ONLY in its
// first two phases (all 24 frags held in regs), so its buffer is dead after ph2
// and prefetch of t+2 starts at ph3. vmcnt(6) at ph4/ph8 keeps 3 half-tiles
// (6 loads/wave) in flight; never drains to 0 except the last iteration.
#define G256_BAR() asm volatile("s_barrier" ::: "memory")

__device__ __forceinline__ void g256_stage_half(
    const bf16* __restrict__ base, int ldx, int tile, int half,
    unsigned op_byte, unsigned short* lds, int trow, int tcol8, int wave) {
  const bf16* g0 = base + (size_t)(half * 128 + trow) * ldx + tile * 64 + tcol8;
  const bf16* g1 = g0 + (size_t)64 * ldx;
  unsigned off = op_byte + (unsigned)(tile & 1) * 32768u + (unsigned)half * 16384u +
                 (unsigned)wave * 1024u;
  unsigned l0 = (unsigned)(size_t)((char*)lds + off);
  unsigned l1 = l0 + 8192u;
  __builtin_amdgcn_global_load_lds(
      (const __attribute__((address_space(1))) void*)(size_t)g0,
      (__attribute__((address_space(3))) unsigned int*)l0, 16, 0, 0);
  __builtin_amdgcn_global_load_lds(
      (const __attribute__((address_space(1))) void*)(size_t)g1,
      (__attribute__((address_space(3))) unsigned int*)l1, 16, 0, 0);
}

__device__ __forceinline__ void g256_read_a(
    const unsigned short* lds, int buf, int sel, int wm, int l15, int quad,
    s8v out[4][2]) {
  int xr = l15 & 7;
#pragma unroll
  for (int i = 0; i < 4; i++) {
    int R = wm * 128 + sel * 64 + i * 16 + l15;
#pragma unroll
    for (int kk = 0; kk < 2; kk++) {
      int ch = (kk * 4 + quad) ^ xr;
      out[i][kk] = *(const s8v*)&lds[buf * 16384 + R * 64 + ch * 8];
    }
  }
}

__device__ __forceinline__ void g256_read_b(
    const unsigned short* lds, int buf, int sel, int wn, int l15, int quad,
    s8v out[2][2]) {
  int xr = l15 & 7;
#pragma unroll
  for (int j = 0; j < 2; j++) {
    int R = wn * 64 + sel * 32 + j * 16 + l15;
#pragma unroll
    for (int kk = 0; kk < 2; kk++) {
      int ch = (kk * 4 + quad) ^ xr;
      out[j][kk] = *(const s8v*)&lds[32768 + buf * 16384 + R * 64 + ch * 8];
    }
  }
}

__device__ __forceinline__ void g256_mfma_quad(
    const s8v a[4][2], const s8v b[2][2], f4v acc[8][4], int ag, int bg) {
  __builtin_amdgcn_s_setprio(1);
#pragma unroll
  for (int i = 0; i < 4; i++)
#pragma unroll
    for (int j = 0; j < 2; j++)
#pragma unroll
      for (int kk = 0; kk < 2; kk++)
        acc[ag * 4 + i][bg * 2 + j] = __builtin_amdgcn_mfma_f32_16x16x32_bf16(
            a[i][kk], b[j][kk], acc[ag * 4 + i][bg * 2 + j], 0, 0, 0);
  __builtin_amdgcn_s_setprio(0);
}

template <int GELU>
__global__ __launch_bounds__(512, 2)
void gemm256_kernel(const bf16* __restrict__ A, int lda,
                    const bf16* __restrict__ Bt, int ldb,
                    const float* __restrict__ bias,
                    bf16* __restrict__ C, int ldc,
                    int M, int N, int K) {
  __shared__ __align__(128) unsigned short lds[65536];  // 128 KiB
  int tid = threadIdx.x;
  int lane = tid & 63, wave = tid >> 6;
  int l15 = lane & 15, quad = lane >> 4;
  int wm = wave >> 2, wn = wave & 3;          // 2 x 4 wave grid
  int m0 = blockIdx.y * 256, n0 = blockIdx.x * 256;
  int trow = tid >> 3;                         // 0..63
  int tcol8 = ((tid & 7) ^ ((tid >> 3) & 7)) * 8;  // inverse-swizzled source col
  const bf16* Ag = A + (size_t)m0 * lda;
  const bf16* Bg = Bt + (size_t)n0 * ldb;

  f4v acc[8][4];
#pragma unroll
  for (int i = 0; i < 8; i++)
#pragma unroll
    for (int j = 0; j < 4; j++) acc[i][j] = (f4v){0.f, 0.f, 0.f, 0.f};

  // prologue: tile0 fully, tile1 {A-lo, A-hi, B-lo}; vmcnt(6) -> tile0 landed,
  // 3 half-tiles (6 loads/wave) stay in flight.
  g256_stage_half(Ag, lda, 0, 0, 0, lds, trow, tcol8, wave);
  g256_stage_half(Ag, lda, 0, 1, 0, lds, trow, tcol8, wave);
  g256_stage_half(Bg, ldb, 0, 0, 65536, lds, trow, tcol8, wave);
  g256_stage_half(Bg, ldb, 0, 1, 65536, lds, trow, tcol8, wave);
  g256_stage_half(Ag, lda, 1, 0, 0, lds, trow, tcol8, wave);
  g256_stage_half(Ag, lda, 1, 1, 0, lds, trow, tcol8, wave);
  g256_stage_half(Bg, ldb, 1, 0, 65536, lds, trow, tcol8, wave);
  asm volatile("s_waitcnt vmcnt(6)" ::: "memory");
  G256_BAR();

  int niter = K >> 7;  // 2 K-tiles of 64 per iteration
  for (int it = 0; it < niter; ++it) {
    int t = it * 2;
    bool more = (it < niter - 1);
    s8v a0[4][2], a1[4][2], b0f[2][2], b1f[2][2];
    // ---- ph1: read t.{A0,B0}; stage (t+1).B-hi; MFMA A0B0
    g256_read_a(lds, 0, 0, wm, l15, quad, a0);
    g256_read_b(lds, 0, 0, wn, l15, quad, b0f);
    g256_stage_half(Bg, ldb, t + 1, 1, 65536, lds, trow, tcol8, wave);
    G256_BAR();
    g256_mfma_quad(a0, b0f, acc, 0, 0);
    G256_BAR();
    // ---- ph2: read t.{A1,B1}; MFMA A1B0   (tile t buffers dead after this)
    g256_read_a(lds, 0, 1, wm, l15, quad, a1);
    g256_read_b(lds, 0, 1, wn, l15, quad, b1f);
    G256_BAR();
    g256_mfma_quad(a1, b0f, acc, 1, 0);
    G256_BAR();
    // ---- ph3: stage (t+2).{A-lo,A-hi}; MFMA A1B1
    if (more) {
      g256_stage_half(Ag, lda, t + 2, 0, 0, lds, trow, tcol8, wave);
      g256_stage_half(Ag, lda, t + 2, 1, 0, lds, trow, tcol8, wave);
    }
    G256_BAR();
    g256_mfma_quad(a1, b1f, acc, 1, 1);
    G256_BAR();
    // ---- ph4: stage (t+2).B-lo; MFMA A0B1; vmcnt -> t+1 fully landed
    if (more) g256_stage_half(Bg, ldb, t + 2, 0, 65536, lds, trow, tcol8, wave);
    G256_BAR();
    g256_mfma_quad(a0, b1f, acc, 0, 1);
    if (more) { asm volatile("s_waitcnt vmcnt(6)" ::: "memory"); }
    else      { asm volatile("s_waitcnt vmcnt(0)" ::: "memory"); }
    G256_BAR();
    // ---- ph5: read (t+1).{A0,B0}; stage (t+2).B-hi; MFMA A0B0
    g256_read_a(lds, 1, 0, wm, l15, quad, a0);
    g256_read_b(lds, 1, 0, wn, l15, quad, b0f);
    if (more) g256_stage_half(Bg, ldb, t + 2, 1, 65536, lds, trow, tcol8, wave);
    G256_BAR();
    g256_mfma_quad(a0, b0f, acc, 0, 0);
    G256_BAR();
    // ---- ph6: read (t+1).{A1,B1}; MFMA A1B0
    g256_read_a(lds, 1, 1, wm, l15, quad, a1);
    g256_read_b(lds, 1, 1, wn, l15, quad, b1f);
    G256_BAR();
    g256_mfma_quad(a1, b0f, acc, 1, 0);
    G256_BAR();
    // ---- ph7: stage (t+3).{A-lo,A-hi}; MFMA A1B1
    if (more) {
      g256_stage_half(Ag, lda, t + 3, 0, 0, lds, trow, tcol8, wave);
      g256_stage_half(Ag, lda, t + 3, 1, 0, lds, trow, tcol8, wave);
    }
    G256_BAR();
    g256_mfma_quad(a1, b1f, acc, 1, 1);
    G256_BAR();
    // ---- ph8: stage (t+3).B-lo; MFMA A0B1; vmcnt -> t+2 fully landed
    if (more) g256_stage_half(Bg, ldb, t + 3, 0, 65536, lds, trow, tcol8, wave);
    G256_BAR();
    g256_mfma_quad(a0, b1f, acc, 0, 1);
    if (more) asm volatile("s_waitcnt vmcnt(6)" ::: "memory");
    G256_BAR();
  }

  // epilogue: bias (+GELU) + bf16 store
#pragma unroll
  for (int sa = 0; sa < 2; sa++)
#pragma unroll
    for (int i = 0; i < 4; i++)
#pragma unroll
      for (int sb = 0; sb < 2; sb++)
#pragma unroll
        for (int j = 0; j < 2; j++) {
          int n = n0 + wn * 64 + sb * 32 + j * 16 + l15;
          float bval = bias[n];
#pragma unroll
          for (int r = 0; r < 4; r++) {
            int m = m0 + wm * 128 + sa * 64 + i * 16 + quad * 4 + r;
            float v = acc[sa * 4 + i][sb * 2 + j][r] + bval;
            if (GELU) v = 0.5f * v * (1.f + erff(v * 0.70710678118654752f));
            C[(size_t)m * ldc + n] = f2bf(v);
          }
        }
}

// ---- softmax over last dim of scores [128*512 rows][512], bf16 in-place -------
__global__ void softmax_kernel(bf16* __restrict__ sc) {
  int wave = threadIdx.x >> 6, lane = threadIdx.x & 63;
  size_t row = (size_t)blockIdx.x * 4 + wave;
  unsigned short* p = (unsigned short*)sc + row * SS + lane * 8;
  union { uint4 u4; unsigned short u[8]; } buf;
  buf.u4 = *(const uint4*)p;
  float v[8];
  float mx = -1e30f;
#pragma unroll
  for (int j = 0; j < 8; j++) { v[j] = us2f(buf.u[j]); mx = fmaxf(mx, v[j]); }
#pragma unroll
  for (int off = 32; off > 0; off >>= 1) mx = fmaxf(mx, __shfl_xor(mx, off));
  float sum = 0.f;
#pragma unroll
  for (int j = 0; j < 8; j++) { v[j] = __expf(v[j] - mx); sum += v[j]; }
#pragma unroll
  for (int off = 32; off > 0; off >>= 1) sum += __shfl_xor(sum, off);
  float inv = 1.f / sum;
  union { uint4 u4; unsigned short u[8]; } obuf;
#pragma unroll
  for (int j = 0; j < 8; j++) {
    bf16 b = f2bf(v[j] * inv);
    obuf.u[j] = *(unsigned short*)&b;
  }
  *(uint4*)p = obuf.u4;
}

// ---------------- launch ----------------
extern "C" void kernel_launch(void* const* d_in, const int* in_sizes, int n_in,
                              void* d_out, int out_size, void* d_ws, size_t ws_size,
                              hipStream_t stream) {
  const float* x     = (const float*)d_in[0];
  const float* pos   = (const float*)d_in[1];
  const float* eg    = (const float*)d_in[2];
  const float* ebeta = (const float*)d_in[3];
  const float* Wq    = (const float*)d_in[4];
  const float* Wk    = (const float*)d_in[5];
  const float* Wv    = (const float*)d_in[6];
  const float* qbias = (const float*)d_in[7];
  const float* vbias = (const float*)d_in[8];
  const float* Wo    = (const float*)d_in[9];
  const float* bo    = (const float*)d_in[10];
  const float* l1g   = (const float*)d_in[11];
  const float* l1b   = (const float*)d_in[12];
  const float* Wi    = (const float*)d_in[13];
  const float* bi    = (const float*)d_in[14];
  const float* Wf    = (const float*)d_in[15];
  const float* bfb   = (const float*)d_in[16];
  const float* l2g   = (const float*)d_in[17];
  const float* l2b   = (const float*)d_in[18];

  // --- workspace (256 MiB): [MiB offsets] ---
  char* w = (char*)d_ws;
  const size_t MB = (size_t)1 << 20;
  bf16* h      = (bf16*)(w + 0 * MB);     // 16
  bf16* qkv    = (bf16*)(w + 16 * MB);    // 48: [T][3H] fused q|k|v
  bf16* ctx    = (bf16*)(w + 64 * MB);    // 16
  bf16* tmp1   = (bf16*)(w + 80 * MB);    // 16
  bf16* attn   = (bf16*)(w + 96 * MB);    // 16
  bf16* scores = (bf16*)(w + 112 * MB);   // 64 [112,176) live: qk->pv
  bf16* ff     = (bf16*)(w + 112 * MB);   // 48 [112,160) live: Wi->Wf (disjoint)
  bf16* tmp2   = (bf16*)(w + 176 * MB);   // 16
  bf16* vt     = (bf16*)(w + 192 * MB);   // 16
  bf16* Wqkvt  = (bf16*)(w + 208 * MB);   // 6: [3H][H] packed q|k|v rows
  bf16* Wot    = (bf16*)(w + 214 * MB);   // 2
  bf16* Wit    = (bf16*)(w + 216 * MB);   // 6
  bf16* Wft    = (bf16*)(w + 222 * MB);   // 6
  float* qkvb  = (float*)(w + 228 * MB);  // 12 KB
  float* out   = (float*)d_out;

  const float QSCALE = 0.08838834764831845f;  // 1/sqrt(128), applied in QK epilogue

  embed_ln_kernel<<<TT, 256, 0, stream>>>(x, pos, eg, ebeta, h);

  convert_w_kernel<<<dim3(HH / 32, HH / 32), 256, 0, stream>>>(Wq, Wqkvt, HH, HH);
  convert_w_kernel<<<dim3(HH / 32, HH / 32), 256, 0, stream>>>(Wk, Wqkvt + (size_t)HH * HH, HH, HH);
  convert_w_kernel<<<dim3(HH / 32, HH / 32), 256, 0, stream>>>(Wv, Wqkvt + (size_t)2 * HH * HH, HH, HH);
  convert_w_kernel<<<dim3(HH / 32, HH / 32), 256, 0, stream>>>(Wo, Wot, HH, HH);
  convert_w_kernel<<<dim3(FFF / 32, HH / 32), 256, 0, stream>>>(Wi, Wit, HH, FFF);
  convert_w_kernel<<<dim3(HH / 32, FFF / 32), 256, 0, stream>>>(Wf, Wft, FFF, HH);
  build_qkv_bias_kernel<<<12, 256, 0, stream>>>(qbias, vbias, qkvb);

  // fused QKV: qkv[8192,3072] = h @ Wqkvt^T + qkvb   (256^2 8-phase)
  gemm256_kernel<0><<<dim3(12, 32), 512, 0, stream>>>(
      h, HH, Wqkvt, HH, qkvb, qkv, 3 * HH, TT, 3 * HH, HH);

  // scores[b,h,512,512] = (q_bh @ k_bh^T) * QSCALE  (k cols of qkv act as Bt)
  mfma_gemm_kernel<0><<<dim3(4, 4, BB * NHH), 256, 0, stream>>>(
      qkv, 3 * HH, (long long)SS * 3 * HH, HDD,
      qkv + HH, 3 * HH, (long long)SS * 3 * HH, HDD,
      nullptr,
      scores, SS, (long long)NHH * SS * SS, (long long)SS * SS,
      SS, SS, HDD, QSCALE);

  softmax_kernel<<<BB * NHH * SS / 4, 256, 0, stream>>>(scores);

  transpose_v_kernel<<<dim3(SS / 32, HDD / 32, BB * NHH), 256, 0, stream>>>(qkv + 2 * HH, vt);

  // ctx_bh[512,128] = probs_bh @ v_bh  (vt[dim][key] is Bt layout)
  mfma_gemm_kernel<0><<<dim3(1, 4, BB * NHH), 256, 0, stream>>>(
      scores, SS, (long long)NHH * SS * SS, (long long)SS * SS,
      vt, SS, (long long)NHH * HDD * SS, (long long)HDD * SS,
      nullptr,
      ctx, HH, (long long)SS * HH, HDD,
      SS, HDD, SS, 1.f);

  gemm256_kernel<0><<<dim3(4, 32), 512, 0, stream>>>(
      ctx, HH, Wot, HH, bo, tmp1, HH, TT, HH, HH);
  add_ln_kernel<0><<<TT, 256, 0, stream>>>(tmp1, h, l1g, l1b, attn);

  gemm256_kernel<1><<<dim3(12, 32), 512, 0, stream>>>(
      attn, HH, Wit, HH, bi, ff, FFF, TT, FFF, HH);
  gemm256_kernel<0><<<dim3(4, 32), 512, 0, stream>>>(
      ff, FFF, Wft, FFF, bfb, tmp2, HH, TT, HH, FFF);
  add_ln_kernel<1><<<TT, 256, 0, stream>>>(tmp2, attn, l2g, l2b, out);
}

// Round 2
// 619.395 us; speedup vs baseline: 1.1207x; 1.1207x over previous
//
#include <hip/hip_runtime.h>
#include <hip/hip_bf16.h>

// DeBERTa layer: B=16,S=512,H=1024,NH=8,HD=128,FF=3072.
// R10: gemm256 LDS reads moved to inline-asm ds_read_b128 (hide LDS RAW from
// compiler alias analysis -> no auto vmcnt(0) drains; manual lgkmcnt(0) +
// sched_barrier(0) per rule #18), builtin s_barrier, phase-edge pinning,
// + bijective XCD swizzle. 128x128 kernel kept for batched QK^T / PV.
#define BB  16
#define SS  512
#define HH  1024
#define NHH 8
#define HDD 128
#define FFF 3072
#define TT  (BB * SS)   // 8192 tokens

typedef __hip_bfloat16 bf16;
typedef short s8v __attribute__((ext_vector_type(8)));   // 8 bf16 bits (4 VGPRs)
typedef float f4v __attribute__((ext_vector_type(4)));   // 4 f32 acc

__device__ __forceinline__ float bf2f(bf16 v) { return __bfloat162float(v); }
__device__ __forceinline__ bf16 f2bf(float f) { return __float2bfloat16(f); }
__device__ __forceinline__ float us2f(unsigned short u) {
  union { unsigned int i; float f; } c; c.i = (unsigned int)u << 16; return c.f;
}

// ---------------- Embedding LayerNorm (f32 in -> bf16 out) ----------------------
__global__ void embed_ln_kernel(const float* __restrict__ x, const float* __restrict__ pos,
                                const float* __restrict__ g, const float* __restrict__ bta,
                                bf16* __restrict__ h) {
  int t = blockIdx.x;
  int s = t & (SS - 1);
  int tid = threadIdx.x;
  const float* xr = x + (size_t)t * HH;
  const float* pr = pos + (size_t)s * HH;
  float vals[4];
  float sum = 0.f;
#pragma unroll
  for (int i = 0; i < 4; i++) {
    int c = tid + i * 256;
    vals[i] = xr[c] + pr[c];
    sum += vals[i];
  }
  __shared__ float red[4];
#pragma unroll
  for (int off = 32; off > 0; off >>= 1) sum += __shfl_down(sum, off, 64);
  if ((tid & 63) == 0) red[tid >> 6] = sum;
  __syncthreads();
  float mean = (red[0] + red[1] + red[2] + red[3]) * (1.f / HH);
  float vsum = 0.f;
#pragma unroll
  for (int i = 0; i < 4; i++) { float d = vals[i] - mean; vsum += d * d; }
  __syncthreads();
#pragma unroll
  for (int off = 32; off > 0; off >>= 1) vsum += __shfl_down(vsum, off, 64);
  if ((tid & 63) == 0) red[tid >> 6] = vsum;
  __syncthreads();
  float rstd = rsqrtf((red[0] + red[1] + red[2] + red[3]) * (1.f / HH) + 1e-7f);
  bf16* hr = h + (size_t)t * HH;
#pragma unroll
  for (int i = 0; i < 4; i++) {
    int c = tid + i * 256;
    hr[c] = f2bf((vals[i] - mean) * rstd * g[c] + bta[c]);
  }
}

// ------- a(bf16)+res(bf16) -> LN -> out (OUT_F32 ? float : bf16) ---------------
template <int OUT_F32>
__global__ void add_ln_kernel(const bf16* __restrict__ a, const bf16* __restrict__ res,
                              const float* __restrict__ g, const float* __restrict__ bta,
                              void* __restrict__ outv) {
  int t = blockIdx.x;
  int tid = threadIdx.x;
  const bf16* ar = a + (size_t)t * HH;
  const bf16* rr = res + (size_t)t * HH;
  float vals[4];
  float sum = 0.f;
#pragma unroll
  for (int i = 0; i < 4; i++) {
    int c = tid + i * 256;
    vals[i] = bf2f(ar[c]) + bf2f(rr[c]);
    sum += vals[i];
  }
  __shared__ float red[4];
#pragma unroll
  for (int off = 32; off > 0; off >>= 1) sum += __shfl_down(sum, off, 64);
  if ((tid & 63) == 0) red[tid >> 6] = sum;
  __syncthreads();
  float mean = (red[0] + red[1] + red[2] + red[3]) * (1.f / HH);
  float vsum = 0.f;
#pragma unroll
  for (int i = 0; i < 4; i++) { float d = vals[i] - mean; vsum += d * d; }
  __syncthreads();
#pragma unroll
  for (int off = 32; off > 0; off >>= 1) vsum += __shfl_xor(vsum, off);
  if ((tid & 63) == 0) red[tid >> 6] = vsum;
  __syncthreads();
  float rstd = rsqrtf((red[0] + red[1] + red[2] + red[3]) * (1.f / HH) + 1e-7f);
#pragma unroll
  for (int i = 0; i < 4; i++) {
    int c = tid + i * 256;
    float o = (vals[i] - mean) * rstd * g[c] + bta[c];
    if (OUT_F32)
      ((float*)outv)[(size_t)t * HH + c] = o;
    else
      ((bf16*)outv)[(size_t)t * HH + c] = f2bf(o);
  }
}

// ---- weight convert+transpose: W[K,N] f32 -> Wt[N,K] bf16 (K fixed per call) --
__global__ void convert_w_kernel(const float* __restrict__ W, bf16* __restrict__ Wt,
                                 int K, int N) {
  __shared__ float tile[32][33];
  int n0 = blockIdx.x * 32, k0 = blockIdx.y * 32;
#pragma unroll
  for (int it = 0; it < 4; it++) {
    int idx = threadIdx.x + it * 256;
    int ty = idx >> 5, tx = idx & 31;
    tile[ty][tx] = W[(size_t)(k0 + ty) * N + n0 + tx];
  }
  __syncthreads();
#pragma unroll
  for (int it = 0; it < 4; it++) {
    int idx = threadIdx.x + it * 256;
    int ty = idx >> 5, tx = idx & 31;
    Wt[(size_t)(n0 + ty) * K + k0 + tx] = f2bf(tile[tx][ty]);
  }
}

// ---- concat qkv bias: [qbias | 0 | vbias] (f32) -------------------------------
__global__ void build_qkv_bias_kernel(const float* __restrict__ qb,
                                      const float* __restrict__ vb,
                                      float* __restrict__ o) {
  int i = blockIdx.x * 256 + threadIdx.x;  // 0..3071
  float v = 0.f;
  if (i < HH) v = qb[i];
  else if (i >= 2 * HH) v = vb[i - 2 * HH];
  o[i] = v;
}

// ---- V transpose per head: qkv v-cols -> vt[b,h,dim,key] (bf16) ---------------
__global__ void transpose_v_kernel(const bf16* __restrict__ v, bf16* __restrict__ vt) {
  __shared__ unsigned short tile[32][33];
  int bh = blockIdx.z;
  int s0 = blockIdx.x * 32, d0 = blockIdx.y * 32;
  int b = bh >> 3, hd = bh & 7;
  const unsigned short* vp = (const unsigned short*)v + ((size_t)b * SS) * (3 * HH) + hd * HDD;
  unsigned short* vtp = (unsigned short*)vt + (size_t)bh * HDD * SS;
#pragma unroll
  for (int it = 0; it < 4; it++) {
    int idx = threadIdx.x + it * 256;
    int ty = idx >> 5, tx = idx & 31;
    tile[ty][tx] = vp[(size_t)(s0 + ty) * (3 * HH) + d0 + tx];
  }
  __syncthreads();
#pragma unroll
  for (int it = 0; it < 4; it++) {
    int idx = threadIdx.x + it * 256;
    int ty = idx >> 5, tx = idx & 31;
    vtp[(size_t)(d0 + ty) * SS + s0 + tx] = tile[tx][ty];
  }
}

// ---- 128x128 MFMA GEMM (kept for batched QK^T / PV) ---------------------------
template <int GELU>
__global__ __launch_bounds__(256)
void mfma_gemm_kernel(const bf16* __restrict__ A, int lda, long long sAb, long long sAh,
                      const bf16* __restrict__ Bt, int ldb, long long sBb, long long sBh,
                      const float* __restrict__ bias,
                      bf16* __restrict__ C, int ldc, long long sCb, long long sCh,
                      int M, int N, int K, float scale) {
  __shared__ unsigned short Als[128 * 40];
  __shared__ unsigned short Bls[128 * 40];
  int tid = threadIdx.x;
  int lane = tid & 63, wave = tid >> 6;
  int l15 = lane & 15, quad = lane >> 4;
  int wm = wave & 1, wn = wave >> 1;
  int m0 = blockIdx.y * 128, n0 = blockIdx.x * 128;
  int zb = blockIdx.z >> 3, zh = blockIdx.z & 7;
  const bf16* Ab = A + zb * sAb + zh * sAh;
  const bf16* Bb = Bt + zb * sBb + zh * sBh;
  bf16* Cb = C + zb * sCb + zh * sCh;
  f4v acc[4][4];
#pragma unroll
  for (int i = 0; i < 4; i++)
#pragma unroll
    for (int j = 0; j < 4; j++) acc[i][j] = (f4v){0.f, 0.f, 0.f, 0.f};
  int r0 = tid >> 2;
  int q8 = (tid & 3) * 8;
  const bf16* Ap0 = Ab + (size_t)(m0 + r0) * lda + q8;
  const bf16* Ap1 = Ab + (size_t)(m0 + r0 + 64) * lda + q8;
  const bf16* Bp0 = Bb + (size_t)(n0 + r0) * ldb + q8;
  const bf16* Bp1 = Bb + (size_t)(n0 + r0 + 64) * ldb + q8;
  uint4 a0 = *(const uint4*)(Ap0);
  uint4 a1 = *(const uint4*)(Ap1);
  uint4 b0 = *(const uint4*)(Bp0);
  uint4 b1 = *(const uint4*)(Bp1);
  for (int k0 = 0; k0 < K; k0 += 32) {
    *(uint4*)&Als[r0 * 40 + q8] = a0;
    *(uint4*)&Als[(r0 + 64) * 40 + q8] = a1;
    *(uint4*)&Bls[r0 * 40 + q8] = b0;
    *(uint4*)&Bls[(r0 + 64) * 40 + q8] = b1;
    __syncthreads();
    int kn = k0 + 32;
    if (kn < K) {
      a0 = *(const uint4*)(Ap0 + kn);
      a1 = *(const uint4*)(Ap1 + kn);
      b0 = *(const uint4*)(Bp0 + kn);
      b1 = *(const uint4*)(Bp1 + kn);
    }
    s8v af[4], bfr[4];
#pragma unroll
    for (int i = 0; i < 4; i++)
      af[i] = *(const s8v*)&Als[(wm * 64 + i * 16 + l15) * 40 + quad * 8];
#pragma unroll
    for (int j = 0; j < 4; j++)
      bfr[j] = *(const s8v*)&Bls[(wn * 64 + j * 16 + l15) * 40 + quad * 8];
#pragma unroll
    for (int i = 0; i < 4; i++)
#pragma unroll
      for (int j = 0; j < 4; j++)
        acc[i][j] = __builtin_amdgcn_mfma_f32_16x16x32_bf16(af[i], bfr[j], acc[i][j], 0, 0, 0);
    __syncthreads();
  }
#pragma unroll
  for (int i = 0; i < 4; i++) {
#pragma unroll
    for (int j = 0; j < 4; j++) {
      int n = n0 + wn * 64 + j * 16 + l15;
      float bval = bias ? bias[n] : 0.f;
#pragma unroll
      for (int r = 0; r < 4; r++) {
        int m = m0 + wm * 64 + i * 16 + quad * 4 + r;
        float v = (acc[i][j][r] + bval) * scale;
        if (GELU) v = 0.5f * v * (1.f + erff(v * 0.70710678118654752f));
        Cb[(size_t)m * ldc + n] = f2bf(v);
      }
    }
  }
}

// =================== 256x256 8-phase dense GEMM ================================
// C[M,N](bf16) = act(A[M,K] @ Bt[N,K]^T + bias).  512 thr = 8 waves (2M x 4N),
// per-wave 128x64 output (acc[8][4] f4v). BK=64, LDS 128 KiB:
//   A: bytes [0,65536)      = 2 bufs x 256 rows x 64 cols bf16 (row = 128 B)
//   B: bytes [65536,131072) = same (rows = n)
// Storage swizzle: 16B chunk c of row r stored at chunk c ^ (r&7). Applied on
// the WRITE side by permuting the per-lane GLOBAL source column (gload_lds
// writes LDS linearly), and on the READ side in the ds_read address.
// All LDS reads are inline-asm ds_read_b128 on 32-bit LDS addresses so the
// compiler cannot see a RAW vs global_load_lds and insert vmcnt(0) drains;
// ordering is manual: counted vmcnt(6) at ph4/ph8, lgkmcnt(0)+sched_barrier(0)
// after each read-phase barrier (rule #18).
__device__ __forceinline__ s8v g256_dsr(unsigned addr) {
  s8v r;
  asm volatile("ds_read_b128 %0, %1" : "=v"(r) : "v"(addr));
  return r;
}

__device__ __forceinline__ void g256_stage_half(
    const bf16* __restrict__ base, int ldx, int tile, int half,
    unsigned op_byte, unsigned lds_base, int trow, int tcol8, int wave) {
  const bf16* g0 = base + (size_t)(half * 128 + trow) * ldx + tile * 64 + tcol8;
  const bf16* g1 = g0 + (size_t)64 * ldx;
  unsigned l0 = lds_base + op_byte + (unsigned)(tile & 1) * 32768u +
                (unsigned)half * 16384u + (unsigned)wave * 1024u;
  unsigned l1 = l0 + 8192u;
  __builtin_amdgcn_global_load_lds(
      (const __attribute__((address_space(1))) void*)(size_t)g0,
      (__attribute__((address_space(3))) unsigned int*)(size_t)l0, 16, 0, 0);
  __builtin_amdgcn_global_load_lds(
      (const __attribute__((address_space(1))) void*)(size_t)g1,
      (__attribute__((address_space(3))) unsigned int*)(size_t)l1, 16, 0, 0);
}

// a_base/b_base precomputed per-thread; addr = base + buf*32768 + sel*rows +
// i*2048, kk toggles chunk bit2 => XOR byte 64 (no carries: chunk bits are 4-6).
__device__ __forceinline__ void g256_read_a_asm(unsigned a_base, int buf, int sel,
                                                s8v out[4][2]) {
  unsigned base = a_base + (unsigned)buf * 32768u + (unsigned)sel * 8192u;
#pragma unroll
  for (int i = 0; i < 4; i++) {
    unsigned r0 = base + (unsigned)i * 2048u;
    out[i][0] = g256_dsr(r0);
    out[i][1] = g256_dsr(r0 ^ 64u);
  }
}

__device__ __forceinline__ void g256_read_b_asm(unsigned b_base, int buf, int sel,
                                                s8v out[2][2]) {
  unsigned base = b_base + (unsigned)buf * 32768u + (unsigned)sel * 4096u;
#pragma unroll
  for (int j = 0; j < 2; j++) {
    unsigned r0 = base + (unsigned)j * 2048u;
    out[j][0] = g256_dsr(r0);
    out[j][1] = g256_dsr(r0 ^ 64u);
  }
}

__device__ __forceinline__ void g256_mfma_quad(
    const s8v a[4][2], const s8v b[2][2], f4v acc[8][4], int ag, int bg) {
  __builtin_amdgcn_s_setprio(1);
#pragma unroll
  for (int i = 0; i < 4; i++)
#pragma unroll
    for (int j = 0; j < 2; j++)
#pragma unroll
      for (int kk = 0; kk < 2; kk++)
        acc[ag * 4 + i][bg * 2 + j] = __builtin_amdgcn_mfma_f32_16x16x32_bf16(
            a[i][kk], b[j][kk], acc[ag * 4 + i][bg * 2 + j], 0, 0, 0);
  __builtin_amdgcn_s_setprio(0);
}

#define G256_SYNC_RD() do {                                \
    __builtin_amdgcn_s_barrier();                          \
    asm volatile("s_waitcnt lgkmcnt(0)" ::: "memory");     \
    __builtin_amdgcn_sched_barrier(0);                     \
  } while (0)
#define G256_SYNC() do {                                   \
    __builtin_amdgcn_s_barrier();                          \
    __builtin_amdgcn_sched_barrier(0);                     \
  } while (0)
#define G256_END() do {                                    \
    __builtin_amdgcn_sched_barrier(0);                     \
    __builtin_amdgcn_s_barrier();                          \
  } while (0)

template <int GELU>
__global__ __launch_bounds__(512, 2)
void gemm256_kernel(const bf16* __restrict__ A, int lda,
                    const bf16* __restrict__ Bt, int ldb,
                    const float* __restrict__ bias,
                    bf16* __restrict__ C, int ldc,
                    int M, int N, int K) {
  __shared__ __align__(128) unsigned short lds[65536];  // 128 KiB
  int tid = threadIdx.x;
  int lane = tid & 63, wave = tid >> 6;
  int l15 = lane & 15, quad = lane >> 4;
  int wm = wave >> 2, wn = wave & 3;          // 2 x 4 wave grid
  // bijective XCD swizzle (all launches have nwg % 8 == 0)
  int nwg = gridDim.x * gridDim.y;
  int wg = blockIdx.y * gridDim.x + blockIdx.x;
  int swz = (wg & 7) * (nwg >> 3) + (wg >> 3);
  int bx = swz % gridDim.x, by = swz / gridDim.x;
  int m0 = by * 256, n0 = bx * 256;
  int trow = tid >> 3;                         // 0..63
  int tcol8 = ((tid & 7) ^ ((tid >> 3) & 7)) * 8;  // inverse-swizzled source col
  const bf16* Ag = A + (size_t)m0 * lda;
  const bf16* Bg = Bt + (size_t)n0 * ldb;
  unsigned lds_base = (unsigned)(size_t)(&lds[0]);  // low 32b of flat = LDS offset
  int xr = l15 & 7;
  unsigned a_base = lds_base + (unsigned)((wm * 128 + l15) * 128 + ((quad ^ xr) << 4));
  unsigned b_base = lds_base + 65536u + (unsigned)((wn * 64 + l15) * 128 + ((quad ^ xr) << 4));

  f4v acc[8][4];
#pragma unroll
  for (int i = 0; i < 8; i++)
#pragma unroll
    for (int j = 0; j < 4; j++) acc[i][j] = (f4v){0.f, 0.f, 0.f, 0.f};

  // prologue: tile0 fully, tile1 {A-lo, A-hi, B-lo}; vmcnt(6) -> tile0 landed,
  // 3 half-tiles (6 loads/wave) stay in flight.
  g256_stage_half(Ag, lda, 0, 0, 0, lds_base, trow, tcol8, wave);
  g256_stage_half(Ag, lda, 0, 1, 0, lds_base, trow, tcol8, wave);
  g256_stage_half(Bg, ldb, 0, 0, 65536, lds_base, trow, tcol8, wave);
  g256_stage_half(Bg, ldb, 0, 1, 65536, lds_base, trow, tcol8, wave);
  g256_stage_half(Ag, lda, 1, 0, 0, lds_base, trow, tcol8, wave);
  g256_stage_half(Ag, lda, 1, 1, 0, lds_base, trow, tcol8, wave);
  g256_stage_half(Bg, ldb, 1, 0, 65536, lds_base, trow, tcol8, wave);
  asm volatile("s_waitcnt vmcnt(6)" ::: "memory");
  __builtin_amdgcn_sched_barrier(0);
  __builtin_amdgcn_s_barrier();

  int niter = K >> 7;  // 2 K-tiles of 64 per iteration
  for (int it = 0; it < niter; ++it) {
    int t = it * 2;
    bool more = (it < niter - 1);
    s8v a0[4][2], a1[4][2], b0f[2][2], b1f[2][2];
    // ---- ph1: read t.{A sel0, B sel0}; stage (t+1).B-hi; MFMA A0B0
    g256_read_a_asm(a_base, 0, 0, a0);
    g256_read_b_asm(b_base, 0, 0, b0f);
    g256_stage_half(Bg, ldb, t + 1, 1, 65536, lds_base, trow, tcol8, wave);
    G256_SYNC_RD();
    g256_mfma_quad(a0, b0f, acc, 0, 0);
    G256_END();
    // ---- ph2: read t.{A sel1, B sel1}; MFMA A1B0  (tile t dead after reads)
    g256_read_a_asm(a_base, 0, 1, a1);
    g256_read_b_asm(b_base, 0, 1, b1f);
    G256_SYNC_RD();
    g256_mfma_quad(a1, b0f, acc, 1, 0);
    G256_END();
    // ---- ph3: stage (t+2).{A-lo,A-hi}; MFMA A1B1
    if (more) {
      g256_stage_half(Ag, lda, t + 2, 0, 0, lds_base, trow, tcol8, wave);
      g256_stage_half(Ag, lda, t + 2, 1, 0, lds_base, trow, tcol8, wave);
    }
    G256_SYNC();
    g256_mfma_quad(a1, b1f, acc, 1, 1);
    G256_END();
    // ---- ph4: stage (t+2).B-lo; MFMA A0B1; vmcnt -> t+1 fully landed
    if (more) g256_stage_half(Bg, ldb, t + 2, 0, 65536, lds_base, trow, tcol8, wave);
    G256_SYNC();
    g256_mfma_quad(a0, b1f, acc, 0, 1);
    if (more) { asm volatile("s_waitcnt vmcnt(6)" ::: "memory"); }
    else      { asm volatile("s_waitcnt vmcnt(0)" ::: "memory"); }
    G256_END();
    // ---- ph5: read (t+1).{A sel0,B sel0}; stage (t+2).B-hi; MFMA A0B0
    g256_read_a_asm(a_base, 1, 0, a0);
    g256_read_b_asm(b_base, 1, 0, b0f);
    if (more) g256_stage_half(Bg, ldb, t + 2, 1, 65536, lds_base, trow, tcol8, wave);
    G256_SYNC_RD();
    g256_mfma_quad(a0, b0f, acc, 0, 0);
    G256_END();
    // ---- ph6: read (t+1).{A sel1,B sel1}; MFMA A1B0
    g256_read_a_asm(a_base, 1, 1, a1);
    g256_read_b_asm(b_base, 1, 1, b1f);
    G256_SYNC_RD();
    g256_mfma_quad(a1, b0f, acc, 1, 0);
    G256_END();
    // ---- ph7: stage (t+3).{A-lo,A-hi}; MFMA A1B1
    if (more) {
      g256_stage_half(Ag, lda, t + 3, 0, 0, lds_base, trow, tcol8, wave);
      g256_stage_half(Ag, lda, t + 3, 1, 0, lds_base, trow, tcol8, wave);
    }
    G256_SYNC();
    g256_mfma_quad(a1, b1f, acc, 1, 1);
    G256_END();
    // ---- ph8: stage (t+3).B-lo; MFMA A0B1; vmcnt -> t+2 fully landed
    if (more) g256_stage_half(Bg, ldb, t + 3, 0, 65536, lds_base, trow, tcol8, wave);
    G256_SYNC();
    g256_mfma_quad(a0, b1f, acc, 0, 1);
    if (more) asm volatile("s_waitcnt vmcnt(6)" ::: "memory");
    G256_END();
  }

  // epilogue: bias (+GELU) + bf16 store
#pragma unroll
  for (int sa = 0; sa < 2; sa++)
#pragma unroll
    for (int i = 0; i < 4; i++)
#pragma unroll
      for (int sb = 0; sb < 2; sb++)
#pragma unroll
        for (int j = 0; j < 2; j++) {
          int n = n0 + wn * 64 + sb * 32 + j * 16 + l15;
          float bval = bias[n];
#pragma unroll
          for (int r = 0; r < 4; r++) {
            int m = m0 + wm * 128 + sa * 64 + i * 16 + quad * 4 + r;
            float v = acc[sa * 4 + i][sb * 2 + j][r] + bval;
            if (GELU) v = 0.5f * v * (1.f + erff(v * 0.70710678118654752f));
            C[(size_t)m * ldc + n] = f2bf(v);
          }
        }
}

// ---- softmax over last dim of scores [128*512 rows][512], bf16 in-place -------
__global__ void softmax_kernel(bf16* __restrict__ sc) {
  int wave = threadIdx.x >> 6, lane = threadIdx.x & 63;
  size_t row = (size_t)blockIdx.x * 4 + wave;
  unsigned short* p = (unsigned short*)sc + row * SS + lane * 8;
  union { uint4 u4; unsigned short u[8]; } buf;
  buf.u4 = *(const uint4*)p;
  float v[8];
  float mx = -1e30f;
#pragma unroll
  for (int j = 0; j < 8; j++) { v[j] = us2f(buf.u[j]); mx = fmaxf(mx, v[j]); }
#pragma unroll
  for (int off = 32; off > 0; off >>= 1) mx = fmaxf(mx, __shfl_xor(mx, off));
  float sum = 0.f;
#pragma unroll
  for (int j = 0; j < 8; j++) { v[j] = __expf(v[j] - mx); sum += v[j]; }
#pragma unroll
  for (int off = 32; off > 0; off >>= 1) sum += __shfl_xor(sum, off);
  float inv = 1.f / sum;
  union { uint4 u4; unsigned short u[8]; } obuf;
#pragma unroll
  for (int j = 0; j < 8; j++) {
    bf16 b = f2bf(v[j] * inv);
    obuf.u[j] = *(unsigned short*)&b;
  }
  *(uint4*)p = obuf.u4;
}

// ---------------- launch ----------------
extern "C" void kernel_launch(void* const* d_in, const int* in_sizes, int n_in,
                              void* d_out, int out_size, void* d_ws, size_t ws_size,
                              hipStream_t stream) {
  const float* x     = (const float*)d_in[0];
  const float* pos   = (const float*)d_in[1];
  const float* eg    = (const float*)d_in[2];
  const float* ebeta = (const float*)d_in[3];
  const float* Wq    = (const float*)d_in[4];
  const float* Wk    = (const float*)d_in[5];
  const float* Wv    = (const float*)d_in[6];
  const float* qbias = (const float*)d_in[7];
  const float* vbias = (const float*)d_in[8];
  const float* Wo    = (const float*)d_in[9];
  const float* bo    = (const float*)d_in[10];
  const float* l1g   = (const float*)d_in[11];
  const float* l1b   = (const float*)d_in[12];
  const float* Wi    = (const float*)d_in[13];
  const float* bi    = (const float*)d_in[14];
  const float* Wf    = (const float*)d_in[15];
  const float* bfb   = (const float*)d_in[16];
  const float* l2g   = (const float*)d_in[17];
  const float* l2b   = (const float*)d_in[18];

  // --- workspace (256 MiB): [MiB offsets] ---
  char* w = (char*)d_ws;
  const size_t MB = (size_t)1 << 20;
  bf16* h      = (bf16*)(w + 0 * MB);     // 16
  bf16* qkv    = (bf16*)(w + 16 * MB);    // 48: [T][3H] fused q|k|v
  bf16* ctx    = (bf16*)(w + 64 * MB);    // 16
  bf16* tmp1   = (bf16*)(w + 80 * MB);    // 16
  bf16* attn   = (bf16*)(w + 96 * MB);    // 16
  bf16* scores = (bf16*)(w + 112 * MB);   // 64 [112,176) live: qk->pv
  bf16* ff     = (bf16*)(w + 112 * MB);   // 48 [112,160) live: Wi->Wf (disjoint)
  bf16* tmp2   = (bf16*)(w + 176 * MB);   // 16
  bf16* vt     = (bf16*)(w + 192 * MB);   // 16
  bf16* Wqkvt  = (bf16*)(w + 208 * MB);   // 6: [3H][H] packed q|k|v rows
  bf16* Wot    = (bf16*)(w + 214 * MB);   // 2
  bf16* Wit    = (bf16*)(w + 216 * MB);   // 6
  bf16* Wft    = (bf16*)(w + 222 * MB);   // 6
  float* qkvb  = (float*)(w + 228 * MB);  // 12 KB
  float* out   = (float*)d_out;

  const float QSCALE = 0.08838834764831845f;  // 1/sqrt(128), applied in QK epilogue

  embed_ln_kernel<<<TT, 256, 0, stream>>>(x, pos, eg, ebeta, h);

  convert_w_kernel<<<dim3(HH / 32, HH / 32), 256, 0, stream>>>(Wq, Wqkvt, HH, HH);
  convert_w_kernel<<<dim3(HH / 32, HH / 32), 256, 0, stream>>>(Wk, Wqkvt + (size_t)HH * HH, HH, HH);
  convert_w_kernel<<<dim3(HH / 32, HH / 32), 256, 0, stream>>>(Wv, Wqkvt + (size_t)2 * HH * HH, HH, HH);
  convert_w_kernel<<<dim3(HH / 32, HH / 32), 256, 0, stream>>>(Wo, Wot, HH, HH);
  convert_w_kernel<<<dim3(FFF / 32, HH / 32), 256, 0, stream>>>(Wi, Wit, HH, FFF);
  convert_w_kernel<<<dim3(HH / 32, FFF / 32), 256, 0, stream>>>(Wf, Wft, FFF, HH);
  build_qkv_bias_kernel<<<12, 256, 0, stream>>>(qbias, vbias, qkvb);

  // fused QKV: qkv[8192,3072] = h @ Wqkvt^T + qkvb   (256^2 8-phase)
  gemm256_kernel<0><<<dim3(12, 32), 512, 0, stream>>>(
      h, HH, Wqkvt, HH, qkvb, qkv, 3 * HH, TT, 3 * HH, HH);

  // scores[b,h,512,512] = (q_bh @ k_bh^T) * QSCALE  (k cols of qkv act as Bt)
  mfma_gemm_kernel<0><<<dim3(4, 4, BB * NHH), 256, 0, stream>>>(
      qkv, 3 * HH, (long long)SS * 3 * HH, HDD,
      qkv + HH, 3 * HH, (long long)SS * 3 * HH, HDD,
      nullptr,
      scores, SS, (long long)NHH * SS * SS, (long long)SS * SS,
      SS, SS, HDD, QSCALE);

  softmax_kernel<<<BB * NHH * SS / 4, 256, 0, stream>>>(scores);

  transpose_v_kernel<<<dim3(SS / 32, HDD / 32, BB * NHH), 256, 0, stream>>>(qkv + 2 * HH, vt);

  // ctx_bh[512,128] = probs_bh @ v_bh  (vt[dim][key] is Bt layout)
  mfma_gemm_kernel<0><<<dim3(1, 4, BB * NHH), 256, 0, stream>>>(
      scores, SS, (long long)NHH * SS * SS, (long long)SS * SS,
      vt, SS, (long long)NHH * HDD * SS, (long long)HDD * SS,
      nullptr,
      ctx, HH, (long long)SS * HH, HDD,
      SS, HDD, SS, 1.f);

  gemm256_kernel<0><<<dim3(4, 32), 512, 0, stream>>>(
      ctx, HH, Wot, HH, bo, tmp1, HH, TT, HH, HH);
  add_ln_kernel<0><<<TT, 256, 0, stream>>>(tmp1, h, l1g, l1b, attn);

  gemm256_kernel<1><<<dim3(12, 32), 512, 0, stream>>>(
      attn, HH, Wit, HH, bi, ff, FFF, TT, FFF, HH);
  gemm256_kernel<0><<<dim3(4, 32), 512, 0, stream>>>(
      ff, FFF, Wft, FFF, bfb, tmp2, HH, TT, HH, FFF);
  add_ln_kernel<1><<<TT, 256, 0, stream>>>(tmp2, attn, l2g, l2b, out);
}

// Round 6
// 566.249 us; speedup vs baseline: 1.2258x; 1.0939x over previous
//
#include <hip/hip_runtime.h>
#include <hip/hip_bf16.h>

// DeBERTa layer: B=16,S=512,H=1024,NH=8,HD=128,FF=3072.
// R14 = R13 resubmitted verbatim (R5 bench was an infra failure, no verdict).
// 128x128 GEMM with m97-style global_load_lds width=16 staging into linear
// LDS (chunk-XOR swizzle both sides), single-buffered, __syncthreads x2 per
// K-step (the refcheck'd 874-912 TF ladder structure).
#define BB  16
#define SS  512
#define HH  1024
#define NHH 8
#define HDD 128
#define FFF 3072
#define TT  (BB * SS)   // 8192 tokens

typedef __hip_bfloat16 bf16;
typedef short s8v __attribute__((ext_vector_type(8)));   // 8 bf16 bits (4 VGPRs)
typedef float f4v __attribute__((ext_vector_type(4)));   // 4 f32 acc

__device__ __forceinline__ float bf2f(bf16 v) { return __bfloat162float(v); }
__device__ __forceinline__ bf16 f2bf(float f) { return __float2bfloat16(f); }
__device__ __forceinline__ float us2f(unsigned short u) {
  union { unsigned int i; float f; } c; c.i = (unsigned int)u << 16; return c.f;
}

// ---------------- Embedding LayerNorm (f32 in -> bf16 out) ----------------------
__global__ void embed_ln_kernel(const float* __restrict__ x, const float* __restrict__ pos,
                                const float* __restrict__ g, const float* __restrict__ bta,
                                bf16* __restrict__ h) {
  int t = blockIdx.x;
  int s = t & (SS - 1);
  int tid = threadIdx.x;
  const float* xr = x + (size_t)t * HH;
  const float* pr = pos + (size_t)s * HH;
  float vals[4];
  float sum = 0.f;
#pragma unroll
  for (int i = 0; i < 4; i++) {
    int c = tid + i * 256;
    vals[i] = xr[c] + pr[c];
    sum += vals[i];
  }
  __shared__ float red[4];
#pragma unroll
  for (int off = 32; off > 0; off >>= 1) sum += __shfl_down(sum, off, 64);
  if ((tid & 63) == 0) red[tid >> 6] = sum;
  __syncthreads();
  float mean = (red[0] + red[1] + red[2] + red[3]) * (1.f / HH);
  float vsum = 0.f;
#pragma unroll
  for (int i = 0; i < 4; i++) { float d = vals[i] - mean; vsum += d * d; }
  __syncthreads();
#pragma unroll
  for (int off = 32; off > 0; off >>= 1) vsum += __shfl_down(vsum, off, 64);
  if ((tid & 63) == 0) red[tid >> 6] = vsum;
  __syncthreads();
  float rstd = rsqrtf((red[0] + red[1] + red[2] + red[3]) * (1.f / HH) + 1e-7f);
  bf16* hr = h + (size_t)t * HH;
#pragma unroll
  for (int i = 0; i < 4; i++) {
    int c = tid + i * 256;
    hr[c] = f2bf((vals[i] - mean) * rstd * g[c] + bta[c]);
  }
}

// ------- a(bf16)+res(bf16) -> LN -> out (OUT_F32 ? float : bf16) ---------------
template <int OUT_F32>
__global__ void add_ln_kernel(const bf16* __restrict__ a, const bf16* __restrict__ res,
                              const float* __restrict__ g, const float* __restrict__ bta,
                              void* __restrict__ outv) {
  int t = blockIdx.x;
  int tid = threadIdx.x;
  const bf16* ar = a + (size_t)t * HH;
  const bf16* rr = res + (size_t)t * HH;
  float vals[4];
  float sum = 0.f;
#pragma unroll
  for (int i = 0; i < 4; i++) {
    int c = tid + i * 256;
    vals[i] = bf2f(ar[c]) + bf2f(rr[c]);
    sum += vals[i];
  }
  __shared__ float red[4];
#pragma unroll
  for (int off = 32; off > 0; off >>= 1) sum += __shfl_down(sum, off, 64);
  if ((tid & 63) == 0) red[tid >> 6] = sum;
  __syncthreads();
  float mean = (red[0] + red[1] + red[2] + red[3]) * (1.f / HH);
  float vsum = 0.f;
#pragma unroll
  for (int i = 0; i < 4; i++) { float d = vals[i] - mean; vsum += d * d; }
  __syncthreads();
#pragma unroll
  for (int off = 32; off > 0; off >>= 1) vsum += __shfl_down(vsum, off, 64);
  if ((tid & 63) == 0) red[tid >> 6] = vsum;
  __syncthreads();
  float rstd = rsqrtf((red[0] + red[1] + red[2] + red[3]) * (1.f / HH) + 1e-7f);
#pragma unroll
  for (int i = 0; i < 4; i++) {
    int c = tid + i * 256;
    float o = (vals[i] - mean) * rstd * g[c] + bta[c];
    if (OUT_F32)
      ((float*)outv)[(size_t)t * HH + c] = o;
    else
      ((bf16*)outv)[(size_t)t * HH + c] = f2bf(o);
  }
}

// ---- weight convert+transpose: W[K,N] f32 -> Wt[N,K] bf16 (K fixed per call) --
__global__ void convert_w_kernel(const float* __restrict__ W, bf16* __restrict__ Wt,
                                 int K, int N) {
  __shared__ float tile[32][33];
  int n0 = blockIdx.x * 32, k0 = blockIdx.y * 32;
#pragma unroll
  for (int it = 0; it < 4; it++) {
    int idx = threadIdx.x + it * 256;
    int ty = idx >> 5, tx = idx & 31;
    tile[ty][tx] = W[(size_t)(k0 + ty) * N + n0 + tx];
  }
  __syncthreads();
#pragma unroll
  for (int it = 0; it < 4; it++) {
    int idx = threadIdx.x + it * 256;
    int ty = idx >> 5, tx = idx & 31;
    Wt[(size_t)(n0 + ty) * K + k0 + tx] = f2bf(tile[tx][ty]);
  }
}

// ---- concat qkv bias: [qbias | 0 | vbias] (f32) -------------------------------
__global__ void build_qkv_bias_kernel(const float* __restrict__ qb,
                                      const float* __restrict__ vb,
                                      float* __restrict__ o) {
  int i = blockIdx.x * 256 + threadIdx.x;  // 0..3071
  float v = 0.f;
  if (i < HH) v = qb[i];
  else if (i >= 2 * HH) v = vb[i - 2 * HH];
  o[i] = v;
}

// ---- V transpose per head: qkv v-cols -> vt[b,h,dim,key] (bf16) ---------------
__global__ void transpose_v_kernel(const bf16* __restrict__ v, bf16* __restrict__ vt) {
  __shared__ unsigned short tile[32][33];
  int bh = blockIdx.z;
  int s0 = blockIdx.x * 32, d0 = blockIdx.y * 32;
  int b = bh >> 3, hd = bh & 7;
  const unsigned short* vp = (const unsigned short*)v + ((size_t)b * SS) * (3 * HH) + hd * HDD;
  unsigned short* vtp = (unsigned short*)vt + (size_t)bh * HDD * SS;
#pragma unroll
  for (int it = 0; it < 4; it++) {
    int idx = threadIdx.x + it * 256;
    int ty = idx >> 5, tx = idx & 31;
    tile[ty][tx] = vp[(size_t)(s0 + ty) * (3 * HH) + d0 + tx];
  }
  __syncthreads();
#pragma unroll
  for (int it = 0; it < 4; it++) {
    int idx = threadIdx.x + it * 256;
    int ty = idx >> 5, tx = idx & 31;
    vtp[(size_t)(d0 + ty) * SS + s0 + tx] = tile[tx][ty];
  }
}

// ---- Unified 128x128 MFMA GEMM, m97-style global_load_lds staging -------------
// C[M,N](bf16) = act((A[M,K] @ Bt[N,K]^T + bias)*scale). BK=32, 4 waves x 4x4
// mfma_f32_16x16x32_bf16. LDS linear [128][32] ushorts per operand (64B rows):
// thread t stages 16B -> (row=t>>2, chunk=t&3); hi segment (rows 64..127)
// starts at element 2048 (64 rows * 32). Chunk-XOR swizzle (chunk ^= row&3)
// applied on the per-lane GLOBAL source column and mirrored in the read
// index -> wave's ds_read_b128 spreads over all 8 bank-quads (zero extra
// conflict). __syncthreads (vmcnt drain) orders DMA -> reads (m97 pattern).
template <int GELU>
__global__ __launch_bounds__(256)
void mfma_gemm_kernel(const bf16* __restrict__ A, int lda, long long sAb, long long sAh,
                      const bf16* __restrict__ Bt, int ldb, long long sBb, long long sBh,
                      const float* __restrict__ bias,
                      bf16* __restrict__ C, int ldc, long long sCb, long long sCh,
                      int M, int N, int K, float scale) {
  __shared__ __align__(16) unsigned short Als[128 * 32];
  __shared__ __align__(16) unsigned short Bls[128 * 32];
  int tid = threadIdx.x;
  int lane = tid & 63, wave = tid >> 6;
  int l15 = lane & 15, quad = lane >> 4;
  int wm = wave & 1, wn = wave >> 1;
  int m0 = blockIdx.y * 128, n0 = blockIdx.x * 128;
  int zb = blockIdx.z >> 3, zh = blockIdx.z & 7;
  const bf16* Ab = A + zb * sAb + zh * sAh;
  const bf16* Bb = Bt + zb * sBb + zh * sBh;
  bf16* Cb = C + zb * sCb + zh * sCh;
  f4v acc[4][4];
#pragma unroll
  for (int i = 0; i < 4; i++)
#pragma unroll
    for (int j = 0; j < 4; j++) acc[i][j] = (f4v){0.f, 0.f, 0.f, 0.f};

  int srow = tid >> 2;                               // 0..63 staging row
  int scol = ((tid & 3) ^ (srow & 3)) * 8;           // inverse-swizzled src col
  const bf16* ApLo = Ab + (size_t)(m0 + srow) * lda + scol;
  const bf16* ApHi = Ab + (size_t)(m0 + srow + 64) * lda + scol;
  const bf16* BpLo = Bb + (size_t)(n0 + srow) * ldb + scol;
  const bf16* BpHi = Bb + (size_t)(n0 + srow + 64) * ldb + scol;
  // LDS dests: thread t -> byte t*16 within segment; hi segment at +2048 ushorts
  unsigned lA0 = (unsigned)(size_t)(Als + tid * 8);
  unsigned lA1 = (unsigned)(size_t)(Als + 2048 + tid * 8);
  unsigned lB0 = (unsigned)(size_t)(Bls + tid * 8);
  unsigned lB1 = (unsigned)(size_t)(Bls + 2048 + tid * 8);

  for (int k0 = 0; k0 < K; k0 += 32) {
    __builtin_amdgcn_global_load_lds(
        (const __attribute__((address_space(1))) void*)(ApLo + k0),
        (__attribute__((address_space(3))) unsigned int*)(size_t)lA0, 16, 0, 0);
    __builtin_amdgcn_global_load_lds(
        (const __attribute__((address_space(1))) void*)(ApHi + k0),
        (__attribute__((address_space(3))) unsigned int*)(size_t)lA1, 16, 0, 0);
    __builtin_amdgcn_global_load_lds(
        (const __attribute__((address_space(1))) void*)(BpLo + k0),
        (__attribute__((address_space(3))) unsigned int*)(size_t)lB0, 16, 0, 0);
    __builtin_amdgcn_global_load_lds(
        (const __attribute__((address_space(1))) void*)(BpHi + k0),
        (__attribute__((address_space(3))) unsigned int*)(size_t)lB1, 16, 0, 0);
    __syncthreads();   // drains vmcnt -> DMA landed; orders reads below
    s8v af[4], bfr[4];
#pragma unroll
    for (int i = 0; i < 4; i++) {
      int R = wm * 64 + i * 16 + l15;
      af[i] = *(const s8v*)&Als[R * 32 + ((quad ^ (R & 3)) * 8)];
    }
#pragma unroll
    for (int j = 0; j < 4; j++) {
      int R = wn * 64 + j * 16 + l15;
      bfr[j] = *(const s8v*)&Bls[R * 32 + ((quad ^ (R & 3)) * 8)];
    }
#pragma unroll
    for (int i = 0; i < 4; i++)
#pragma unroll
      for (int j = 0; j < 4; j++)
        acc[i][j] = __builtin_amdgcn_mfma_f32_16x16x32_bf16(af[i], bfr[j], acc[i][j], 0, 0, 0);
    __syncthreads();   // all waves done reading before next stage overwrites
  }
#pragma unroll
  for (int i = 0; i < 4; i++) {
#pragma unroll
    for (int j = 0; j < 4; j++) {
      int n = n0 + wn * 64 + j * 16 + l15;
      float bval = bias ? bias[n] : 0.f;
#pragma unroll
      for (int r = 0; r < 4; r++) {
        int m = m0 + wm * 64 + i * 16 + quad * 4 + r;
        float v = (acc[i][j][r] + bval) * scale;
        if (GELU) v = 0.5f * v * (1.f + erff(v * 0.70710678118654752f));
        Cb[(size_t)m * ldc + n] = f2bf(v);
      }
    }
  }
}

// ---- softmax over last dim of scores [128*512 rows][512], bf16 in-place -------
__global__ void softmax_kernel(bf16* __restrict__ sc) {
  int wave = threadIdx.x >> 6, lane = threadIdx.x & 63;
  size_t row = (size_t)blockIdx.x * 4 + wave;
  unsigned short* p = (unsigned short*)sc + row * SS + lane * 8;
  union { uint4 u4; unsigned short u[8]; } buf;
  buf.u4 = *(const uint4*)p;
  float v[8];
  float mx = -1e30f;
#pragma unroll
  for (int j = 0; j < 8; j++) { v[j] = us2f(buf.u[j]); mx = fmaxf(mx, v[j]); }
#pragma unroll
  for (int off = 32; off > 0; off >>= 1) mx = fmaxf(mx, __shfl_xor(mx, off));
  float sum = 0.f;
#pragma unroll
  for (int j = 0; j < 8; j++) { v[j] = __expf(v[j] - mx); sum += v[j]; }
#pragma unroll
  for (int off = 32; off > 0; off >>= 1) sum += __shfl_xor(sum, off);
  float inv = 1.f / sum;
  union { uint4 u4; unsigned short u[8]; } obuf;
#pragma unroll
  for (int j = 0; j < 8; j++) {
    bf16 b = f2bf(v[j] * inv);
    obuf.u[j] = *(unsigned short*)&b;
  }
  *(uint4*)p = obuf.u4;
}

// ---------------- launch ----------------
extern "C" void kernel_launch(void* const* d_in, const int* in_sizes, int n_in,
                              void* d_out, int out_size, void* d_ws, size_t ws_size,
                              hipStream_t stream) {
  const float* x     = (const float*)d_in[0];
  const float* pos   = (const float*)d_in[1];
  const float* eg    = (const float*)d_in[2];
  const float* ebeta = (const float*)d_in[3];
  const float* Wq    = (const float*)d_in[4];
  const float* Wk    = (const float*)d_in[5];
  const float* Wv    = (const float*)d_in[6];
  const float* qbias = (const float*)d_in[7];
  const float* vbias = (const float*)d_in[8];
  const float* Wo    = (const float*)d_in[9];
  const float* bo    = (const float*)d_in[10];
  const float* l1g   = (const float*)d_in[11];
  const float* l1b   = (const float*)d_in[12];
  const float* Wi    = (const float*)d_in[13];
  const float* bi    = (const float*)d_in[14];
  const float* Wf    = (const float*)d_in[15];
  const float* bfb   = (const float*)d_in[16];
  const float* l2g   = (const float*)d_in[17];
  const float* l2b   = (const float*)d_in[18];

  // --- workspace (256 MiB): [MiB offsets] ---
  char* w = (char*)d_ws;
  const size_t MB = (size_t)1 << 20;
  bf16* h      = (bf16*)(w + 0 * MB);     // 16
  bf16* qkv    = (bf16*)(w + 16 * MB);    // 48: [T][3H] fused q|k|v
  bf16* ctx    = (bf16*)(w + 64 * MB);    // 16
  bf16* tmp1   = (bf16*)(w + 80 * MB);    // 16
  bf16* attn   = (bf16*)(w + 96 * MB);    // 16
  bf16* scores = (bf16*)(w + 112 * MB);   // 64 [112,176) live: qk->pv
  bf16* ff     = (bf16*)(w + 112 * MB);   // 48 [112,160) live: Wi->Wf (disjoint)
  bf16* tmp2   = (bf16*)(w + 176 * MB);   // 16
  bf16* vt     = (bf16*)(w + 192 * MB);   // 16
  bf16* Wqkvt  = (bf16*)(w + 208 * MB);   // 6: [3H][H] packed q|k|v rows
  bf16* Wot    = (bf16*)(w + 214 * MB);   // 2
  bf16* Wit    = (bf16*)(w + 216 * MB);   // 6
  bf16* Wft    = (bf16*)(w + 222 * MB);   // 6
  float* qkvb  = (float*)(w + 228 * MB);  // 12 KB
  float* out   = (float*)d_out;

  const float QSCALE = 0.08838834764831845f;  // 1/sqrt(128), applied in QK epilogue

  embed_ln_kernel<<<TT, 256, 0, stream>>>(x, pos, eg, ebeta, h);

  convert_w_kernel<<<dim3(HH / 32, HH / 32), 256, 0, stream>>>(Wq, Wqkvt, HH, HH);
  convert_w_kernel<<<dim3(HH / 32, HH / 32), 256, 0, stream>>>(Wk, Wqkvt + (size_t)HH * HH, HH, HH);
  convert_w_kernel<<<dim3(HH / 32, HH / 32), 256, 0, stream>>>(Wv, Wqkvt + (size_t)2 * HH * HH, HH, HH);
  convert_w_kernel<<<dim3(HH / 32, HH / 32), 256, 0, stream>>>(Wo, Wot, HH, HH);
  convert_w_kernel<<<dim3(FFF / 32, HH / 32), 256, 0, stream>>>(Wi, Wit, HH, FFF);
  convert_w_kernel<<<dim3(HH / 32, FFF / 32), 256, 0, stream>>>(Wf, Wft, FFF, HH);
  build_qkv_bias_kernel<<<12, 256, 0, stream>>>(qbias, vbias, qkvb);

  // fused QKV: qkv[8192,3072] = h @ Wqkvt^T + qkvb
  mfma_gemm_kernel<0><<<dim3(24, 64, 1), 256, 0, stream>>>(
      h, HH, 0, 0, Wqkvt, HH, 0, 0, qkvb, qkv, 3 * HH, 0, 0, TT, 3 * HH, HH, 1.f);

  // scores[b,h,512,512] = (q_bh @ k_bh^T) * QSCALE  (k cols of qkv act as Bt)
  mfma_gemm_kernel<0><<<dim3(4, 4, BB * NHH), 256, 0, stream>>>(
      qkv, 3 * HH, (long long)SS * 3 * HH, HDD,
      qkv + HH, 3 * HH, (long long)SS * 3 * HH, HDD,
      nullptr,
      scores, SS, (long long)NHH * SS * SS, (long long)SS * SS,
      SS, SS, HDD, QSCALE);

  softmax_kernel<<<BB * NHH * SS / 4, 256, 0, stream>>>(scores);

  transpose_v_kernel<<<dim3(SS / 32, HDD / 32, BB * NHH), 256, 0, stream>>>(qkv + 2 * HH, vt);

  // ctx_bh[512,128] = probs_bh @ v_bh  (vt[dim][key] is Bt layout)
  mfma_gemm_kernel<0><<<dim3(1, 4, BB * NHH), 256, 0, stream>>>(
      scores, SS, (long long)NHH * SS * SS, (long long)SS * SS,
      vt, SS, (long long)NHH * HDD * SS, (long long)HDD * SS,
      nullptr,
      ctx, HH, (long long)SS * HH, HDD,
      SS, HDD, SS, 1.f);

  mfma_gemm_kernel<0><<<dim3(8, 64, 1), 256, 0, stream>>>(
      ctx, HH, 0, 0, Wot, HH, 0, 0, bo, tmp1, HH, 0, 0, TT, HH, HH, 1.f);
  add_ln_kernel<0><<<TT, 256, 0, stream>>>(tmp1, h, l1g, l1b, attn);

  mfma_gemm_kernel<1><<<dim3(24, 64, 1), 256, 0, stream>>>(
      attn, HH, 0, 0, Wit, HH, 0, 0, bi, ff, FFF, 0, 0, TT, FFF, HH, 1.f);
  mfma_gemm_kernel<0><<<dim3(8, 64, 1), 256, 0, stream>>>(
      ff, FFF, 0, 0, Wft, FFF, 0, 0, bfb, tmp2, HH, 0, 0, TT, HH, FFF, 1.f);
  add_ln_kernel<1><<<TT, 256, 0, stream>>>(tmp2, attn, l2g, l2b, out);
}

// Round 7
// 529.295 us; speedup vs baseline: 1.3114x; 1.0698x over previous
//
#include <hip/hip_runtime.h>
#include <hip/hip_bf16.h>

// DeBERTa layer: B=16,S=512,H=1024,NH=8,HD=128,FF=3072.
// R15: within-run A/B on identical-shape GEMMs (QKV vs Wi, both 8192x3072x1024):
//  V1 mfma_gemm_kernel: R0 reg-staging+prefetch, 32-ushort rows, chunk-XOR
//     swizzle f=(row>>1)&3 on ds_write AND ds_read (uniform at 16-lane-group
//     and wave granularity -> conflict-free both sides).
//  V2 gemm_dbuf_kernel: gload_lds width=16 + LDS double-buffer, stage(t+1)
//     issued right after the barrier (drain waits on loads a full MFMA phase
//     old -> latency hidden), one __syncthreads per K-step.
#define BB  16
#define SS  512
#define HH  1024
#define NHH 8
#define HDD 128
#define FFF 3072
#define TT  (BB * SS)   // 8192 tokens

typedef __hip_bfloat16 bf16;
typedef short s8v __attribute__((ext_vector_type(8)));   // 8 bf16 bits (4 VGPRs)
typedef float f4v __attribute__((ext_vector_type(4)));   // 4 f32 acc

__device__ __forceinline__ float bf2f(bf16 v) { return __bfloat162float(v); }
__device__ __forceinline__ bf16 f2bf(float f) { return __float2bfloat16(f); }
__device__ __forceinline__ float us2f(unsigned short u) {
  union { unsigned int i; float f; } c; c.i = (unsigned int)u << 16; return c.f;
}

// ---------------- Embedding LayerNorm (f32 in -> bf16 out) ----------------------
__global__ void embed_ln_kernel(const float* __restrict__ x, const float* __restrict__ pos,
                                const float* __restrict__ g, const float* __restrict__ bta,
                                bf16* __restrict__ h) {
  int t = blockIdx.x;
  int s = t & (SS - 1);
  int tid = threadIdx.x;
  const float* xr = x + (size_t)t * HH;
  const float* pr = pos + (size_t)s * HH;
  float vals[4];
  float sum = 0.f;
#pragma unroll
  for (int i = 0; i < 4; i++) {
    int c = tid + i * 256;
    vals[i] = xr[c] + pr[c];
    sum += vals[i];
  }
  __shared__ float red[4];
#pragma unroll
  for (int off = 32; off > 0; off >>= 1) sum += __shfl_down(sum, off, 64);
  if ((tid & 63) == 0) red[tid >> 6] = sum;
  __syncthreads();
  float mean = (red[0] + red[1] + red[2] + red[3]) * (1.f / HH);
  float vsum = 0.f;
#pragma unroll
  for (int i = 0; i < 4; i++) { float d = vals[i] - mean; vsum += d * d; }
  __syncthreads();
#pragma unroll
  for (int off = 32; off > 0; off >>= 1) vsum += __shfl_down(vsum, off, 64);
  if ((tid & 63) == 0) red[tid >> 6] = vsum;
  __syncthreads();
  float rstd = rsqrtf((red[0] + red[1] + red[2] + red[3]) * (1.f / HH) + 1e-7f);
  bf16* hr = h + (size_t)t * HH;
#pragma unroll
  for (int i = 0; i < 4; i++) {
    int c = tid + i * 256;
    hr[c] = f2bf((vals[i] - mean) * rstd * g[c] + bta[c]);
  }
}

// ------- a(bf16)+res(bf16) -> LN -> out (OUT_F32 ? float : bf16) ---------------
template <int OUT_F32>
__global__ void add_ln_kernel(const bf16* __restrict__ a, const bf16* __restrict__ res,
                              const float* __restrict__ g, const float* __restrict__ bta,
                              void* __restrict__ outv) {
  int t = blockIdx.x;
  int tid = threadIdx.x;
  const bf16* ar = a + (size_t)t * HH;
  const bf16* rr = res + (size_t)t * HH;
  float vals[4];
  float sum = 0.f;
#pragma unroll
  for (int i = 0; i < 4; i++) {
    int c = tid + i * 256;
    vals[i] = bf2f(ar[c]) + bf2f(rr[c]);
    sum += vals[i];
  }
  __shared__ float red[4];
#pragma unroll
  for (int off = 32; off > 0; off >>= 1) sum += __shfl_down(sum, off, 64);
  if ((tid & 63) == 0) red[tid >> 6] = sum;
  __syncthreads();
  float mean = (red[0] + red[1] + red[2] + red[3]) * (1.f / HH);
  float vsum = 0.f;
#pragma unroll
  for (int i = 0; i < 4; i++) { float d = vals[i] - mean; vsum += d * d; }
  __syncthreads();
#pragma unroll
  for (int off = 32; off > 0; off >>= 1) vsum += __shfl_down(vsum, off, 64);
  if ((tid & 63) == 0) red[tid >> 6] = vsum;
  __syncthreads();
  float rstd = rsqrtf((red[0] + red[1] + red[2] + red[3]) * (1.f / HH) + 1e-7f);
#pragma unroll
  for (int i = 0; i < 4; i++) {
    int c = tid + i * 256;
    float o = (vals[i] - mean) * rstd * g[c] + bta[c];
    if (OUT_F32)
      ((float*)outv)[(size_t)t * HH + c] = o;
    else
      ((bf16*)outv)[(size_t)t * HH + c] = f2bf(o);
  }
}

// ---- weight convert+transpose: W[K,N] f32 -> Wt[N,K] bf16 (K fixed per call) --
__global__ void convert_w_kernel(const float* __restrict__ W, bf16* __restrict__ Wt,
                                 int K, int N) {
  __shared__ float tile[32][33];
  int n0 = blockIdx.x * 32, k0 = blockIdx.y * 32;
#pragma unroll
  for (int it = 0; it < 4; it++) {
    int idx = threadIdx.x + it * 256;
    int ty = idx >> 5, tx = idx & 31;
    tile[ty][tx] = W[(size_t)(k0 + ty) * N + n0 + tx];
  }
  __syncthreads();
#pragma unroll
  for (int it = 0; it < 4; it++) {
    int idx = threadIdx.x + it * 256;
    int ty = idx >> 5, tx = idx & 31;
    Wt[(size_t)(n0 + ty) * K + k0 + tx] = f2bf(tile[tx][ty]);
  }
}

// ---- concat qkv bias: [qbias | 0 | vbias] (f32) -------------------------------
__global__ void build_qkv_bias_kernel(const float* __restrict__ qb,
                                      const float* __restrict__ vb,
                                      float* __restrict__ o) {
  int i = blockIdx.x * 256 + threadIdx.x;  // 0..3071
  float v = 0.f;
  if (i < HH) v = qb[i];
  else if (i >= 2 * HH) v = vb[i - 2 * HH];
  o[i] = v;
}

// ---- V transpose per head: qkv v-cols -> vt[b,h,dim,key] (bf16) ---------------
__global__ void transpose_v_kernel(const bf16* __restrict__ v, bf16* __restrict__ vt) {
  __shared__ unsigned short tile[32][33];
  int bh = blockIdx.z;
  int s0 = blockIdx.x * 32, d0 = blockIdx.y * 32;
  int b = bh >> 3, hd = bh & 7;
  const unsigned short* vp = (const unsigned short*)v + ((size_t)b * SS) * (3 * HH) + hd * HDD;
  unsigned short* vtp = (unsigned short*)vt + (size_t)bh * HDD * SS;
#pragma unroll
  for (int it = 0; it < 4; it++) {
    int idx = threadIdx.x + it * 256;
    int ty = idx >> 5, tx = idx & 31;
    tile[ty][tx] = vp[(size_t)(s0 + ty) * (3 * HH) + d0 + tx];
  }
  __syncthreads();
#pragma unroll
  for (int it = 0; it < 4; it++) {
    int idx = threadIdx.x + it * 256;
    int ty = idx >> 5, tx = idx & 31;
    vtp[(size_t)(d0 + ty) * SS + s0 + tx] = tile[tx][ty];
  }
}

// ---- V1: 128x128 MFMA GEMM, reg-staging + prefetch + uniform swizzle ----------
// C = act((A @ Bt^T + bias)*scale). BK=32, 4 waves x 4x4 16x16x32 MFMA.
// LDS [128][32] ushorts. Chunk c of row r stored at pos c ^ ((r>>1)&3):
// uniform over the 8 16B-slots at 16-lane-group granularity on BOTH ds_write
// and ds_read (write was R0's conflict source). Next-tile global loads issued
// between the barriers (in flight during ds_read+MFMA) — R0's proven pipeline.
template <int GELU>
__global__ __launch_bounds__(256)
void mfma_gemm_kernel(const bf16* __restrict__ A, int lda, long long sAb, long long sAh,
                      const bf16* __restrict__ Bt, int ldb, long long sBb, long long sBh,
                      const float* __restrict__ bias,
                      bf16* __restrict__ C, int ldc, long long sCb, long long sCh,
                      int M, int N, int K, float scale) {
  __shared__ __align__(16) unsigned short Als[128 * 32];
  __shared__ __align__(16) unsigned short Bls[128 * 32];
  int tid = threadIdx.x;
  int lane = tid & 63, wave = tid >> 6;
  int l15 = lane & 15, quad = lane >> 4;
  int wm = wave & 1, wn = wave >> 1;
  int m0 = blockIdx.y * 128, n0 = blockIdx.x * 128;
  int zb = blockIdx.z >> 3, zh = blockIdx.z & 7;
  const bf16* Ab = A + zb * sAb + zh * sAh;
  const bf16* Bb = Bt + zb * sBb + zh * sBh;
  bf16* Cb = C + zb * sCb + zh * sCh;
  f4v acc[4][4];
#pragma unroll
  for (int i = 0; i < 4; i++)
#pragma unroll
    for (int j = 0; j < 4; j++) acc[i][j] = (f4v){0.f, 0.f, 0.f, 0.f};
  int r0 = tid >> 2;            // 0..63: staging rows r0, r0+64
  int q8 = (tid & 3) * 8;       // global 16B chunk offset (coalesced)
  // write positions: chunk swizzled by f=(row>>1)&3 (same for row and row+64)
  int fw = (r0 >> 1) & 3;
  int wlo = r0 * 32 + (((tid & 3) ^ fw) * 8);
  int whi = (r0 + 64) * 32 + (((tid & 3) ^ fw) * 8);
  // read chunk position: quad ^ ((l15>>1)&3), row-independent
  int qx = (quad ^ ((l15 >> 1) & 3)) * 8;
  const bf16* Ap0 = Ab + (size_t)(m0 + r0) * lda + q8;
  const bf16* Ap1 = Ab + (size_t)(m0 + r0 + 64) * lda + q8;
  const bf16* Bp0 = Bb + (size_t)(n0 + r0) * ldb + q8;
  const bf16* Bp1 = Bb + (size_t)(n0 + r0 + 64) * ldb + q8;
  uint4 a0 = *(const uint4*)(Ap0);
  uint4 a1 = *(const uint4*)(Ap1);
  uint4 b0 = *(const uint4*)(Bp0);
  uint4 b1 = *(const uint4*)(Bp1);
  for (int k0 = 0; k0 < K; k0 += 32) {
    *(uint4*)&Als[wlo] = a0;
    *(uint4*)&Als[whi] = a1;
    *(uint4*)&Bls[wlo] = b0;
    *(uint4*)&Bls[whi] = b1;
    __syncthreads();
    int kn = k0 + 32;
    if (kn < K) {           // issue next tile's loads; in flight during MFMAs
      a0 = *(const uint4*)(Ap0 + kn);
      a1 = *(const uint4*)(Ap1 + kn);
      b0 = *(const uint4*)(Bp0 + kn);
      b1 = *(const uint4*)(Bp1 + kn);
    }
    s8v af[4], bfr[4];
#pragma unroll
    for (int i = 0; i < 4; i++)
      af[i] = *(const s8v*)&Als[(wm * 64 + i * 16 + l15) * 32 + qx];
#pragma unroll
    for (int j = 0; j < 4; j++)
      bfr[j] = *(const s8v*)&Bls[(wn * 64 + j * 16 + l15) * 32 + qx];
#pragma unroll
    for (int i = 0; i < 4; i++)
#pragma unroll
      for (int j = 0; j < 4; j++)
        acc[i][j] = __builtin_amdgcn_mfma_f32_16x16x32_bf16(af[i], bfr[j], acc[i][j], 0, 0, 0);
    __syncthreads();
  }
#pragma unroll
  for (int i = 0; i < 4; i++) {
#pragma unroll
    for (int j = 0; j < 4; j++) {
      int n = n0 + wn * 64 + j * 16 + l15;
      float bval = bias ? bias[n] : 0.f;
#pragma unroll
      for (int r = 0; r < 4; r++) {
        int m = m0 + wm * 64 + i * 16 + quad * 4 + r;
        float v = (acc[i][j][r] + bval) * scale;
        if (GELU) v = 0.5f * v * (1.f + erff(v * 0.70710678118654752f));
        Cb[(size_t)m * ldc + n] = f2bf(v);
      }
    }
  }
}

// ---- V2: 128x128 MFMA GEMM, gload_lds + LDS double-buffer ---------------------
// Stage(t+1) issued right AFTER the __syncthreads that drains tile t -> the
// next drain waits on loads that had a full ds_read+MFMA phase in flight.
// Linear DMA dest (conflict-free); swizzle via global source col permutation
// (chunk s holds global chunk s ^ ((row>>1)&3)); reads as V1.
template <int GELU>
__global__ __launch_bounds__(256)
void gemm_dbuf_kernel(const bf16* __restrict__ A, int lda,
                      const bf16* __restrict__ Bt, int ldb,
                      const float* __restrict__ bias,
                      bf16* __restrict__ C, int ldc,
                      int M, int N, int K, float scale) {
  __shared__ __align__(16) unsigned short As2[2 * 128 * 32];
  __shared__ __align__(16) unsigned short Bs2[2 * 128 * 32];
  int tid = threadIdx.x;
  int lane = tid & 63, wave = tid >> 6;
  int l15 = lane & 15, quad = lane >> 4;
  int wm = wave & 1, wn = wave >> 1;
  int m0 = blockIdx.y * 128, n0 = blockIdx.x * 128;
  f4v acc[4][4];
#pragma unroll
  for (int i = 0; i < 4; i++)
#pragma unroll
    for (int j = 0; j < 4; j++) acc[i][j] = (f4v){0.f, 0.f, 0.f, 0.f};
  int srow = tid >> 2;
  int scol = (((tid & 3) ^ ((tid >> 3) & 3))) * 8;   // inverse-swizzled src col
  const bf16* ApLo = A + (size_t)(m0 + srow) * lda + scol;
  const bf16* ApHi = A + (size_t)(m0 + srow + 64) * lda + scol;
  const bf16* BpLo = Bt + (size_t)(n0 + srow) * ldb + scol;
  const bf16* BpHi = Bt + (size_t)(n0 + srow + 64) * ldb + scol;
  int qx = (quad ^ ((l15 >> 1) & 3)) * 8;
  int niter = K >> 5;

#define V2_STAGE(kk, buf) do {                                                  \
    unsigned _o = (unsigned)(buf) * 4096u + (unsigned)tid * 8u;                 \
    __builtin_amdgcn_global_load_lds(                                           \
        (const __attribute__((address_space(1))) void*)(ApLo + (kk)),           \
        (__attribute__((address_space(3))) unsigned int*)(size_t)               \
            (unsigned)(size_t)(As2 + _o), 16, 0, 0);                            \
    __builtin_amdgcn_global_load_lds(                                           \
        (const __attribute__((address_space(1))) void*)(ApHi + (kk)),           \
        (__attribute__((address_space(3))) unsigned int*)(size_t)               \
            (unsigned)(size_t)(As2 + _o + 2048u), 16, 0, 0);                    \
    __builtin_amdgcn_global_load_lds(                                           \
        (const __attribute__((address_space(1))) void*)(BpLo + (kk)),           \
        (__attribute__((address_space(3))) unsigned int*)(size_t)               \
            (unsigned)(size_t)(Bs2 + _o), 16, 0, 0);                            \
    __builtin_amdgcn_global_load_lds(                                           \
        (const __attribute__((address_space(1))) void*)(BpHi + (kk)),           \
        (__attribute__((address_space(3))) unsigned int*)(size_t)               \
            (unsigned)(size_t)(Bs2 + _o + 2048u), 16, 0, 0);                    \
  } while (0)

  V2_STAGE(0, 0);
  for (int it = 0; it < niter; ++it) {
    __syncthreads();                     // drains vmcnt: tile it landed
    if (it + 1 < niter) V2_STAGE((it + 1) * 32, (it + 1) & 1);
    int buf = it & 1;
    s8v af[4], bfr[4];
#pragma unroll
    for (int i = 0; i < 4; i++)
      af[i] = *(const s8v*)&As2[buf * 4096 + (wm * 64 + i * 16 + l15) * 32 + qx];
#pragma unroll
    for (int j = 0; j < 4; j++)
      bfr[j] = *(const s8v*)&Bs2[buf * 4096 + (wn * 64 + j * 16 + l15) * 32 + qx];
#pragma unroll
    for (int i = 0; i < 4; i++)
#pragma unroll
      for (int j = 0; j < 4; j++)
        acc[i][j] = __builtin_amdgcn_mfma_f32_16x16x32_bf16(af[i], bfr[j], acc[i][j], 0, 0, 0);
  }
#undef V2_STAGE
#pragma unroll
  for (int i = 0; i < 4; i++) {
#pragma unroll
    for (int j = 0; j < 4; j++) {
      int n = n0 + wn * 64 + j * 16 + l15;
      float bval = bias ? bias[n] : 0.f;
#pragma unroll
      for (int r = 0; r < 4; r++) {
        int m = m0 + wm * 64 + i * 16 + quad * 4 + r;
        float v = (acc[i][j][r] + bval) * scale;
        if (GELU) v = 0.5f * v * (1.f + erff(v * 0.70710678118654752f));
        C[(size_t)m * ldc + n] = f2bf(v);
      }
    }
  }
}

// ---- softmax over last dim of scores [128*512 rows][512], bf16 in-place -------
__global__ void softmax_kernel(bf16* __restrict__ sc) {
  int wave = threadIdx.x >> 6, lane = threadIdx.x & 63;
  size_t row = (size_t)blockIdx.x * 4 + wave;
  unsigned short* p = (unsigned short*)sc + row * SS + lane * 8;
  union { uint4 u4; unsigned short u[8]; } buf;
  buf.u4 = *(const uint4*)p;
  float v[8];
  float mx = -1e30f;
#pragma unroll
  for (int j = 0; j < 8; j++) { v[j] = us2f(buf.u[j]); mx = fmaxf(mx, v[j]); }
#pragma unroll
  for (int off = 32; off > 0; off >>= 1) mx = fmaxf(mx, __shfl_xor(mx, off));
  float sum = 0.f;
#pragma unroll
  for (int j = 0; j < 8; j++) { v[j] = __expf(v[j] - mx); sum += v[j]; }
#pragma unroll
  for (int off = 32; off > 0; off >>= 1) sum += __shfl_xor(sum, off);
  float inv = 1.f / sum;
  union { uint4 u4; unsigned short u[8]; } obuf;
#pragma unroll
  for (int j = 0; j < 8; j++) {
    bf16 b = f2bf(v[j] * inv);
    obuf.u[j] = *(unsigned short*)&b;
  }
  *(uint4*)p = obuf.u4;
}

// ---------------- launch ----------------
extern "C" void kernel_launch(void* const* d_in, const int* in_sizes, int n_in,
                              void* d_out, int out_size, void* d_ws, size_t ws_size,
                              hipStream_t stream) {
  const float* x     = (const float*)d_in[0];
  const float* pos   = (const float*)d_in[1];
  const float* eg    = (const float*)d_in[2];
  const float* ebeta = (const float*)d_in[3];
  const float* Wq    = (const float*)d_in[4];
  const float* Wk    = (const float*)d_in[5];
  const float* Wv    = (const float*)d_in[6];
  const float* qbias = (const float*)d_in[7];
  const float* vbias = (const float*)d_in[8];
  const float* Wo    = (const float*)d_in[9];
  const float* bo    = (const float*)d_in[10];
  const float* l1g   = (const float*)d_in[11];
  const float* l1b   = (const float*)d_in[12];
  const float* Wi    = (const float*)d_in[13];
  const float* bi    = (const float*)d_in[14];
  const float* Wf    = (const float*)d_in[15];
  const float* bfb   = (const float*)d_in[16];
  const float* l2g   = (const float*)d_in[17];
  const float* l2b   = (const float*)d_in[18];

  // --- workspace (256 MiB): [MiB offsets] ---
  char* w = (char*)d_ws;
  const size_t MB = (size_t)1 << 20;
  bf16* h      = (bf16*)(w + 0 * MB);     // 16
  bf16* qkv    = (bf16*)(w + 16 * MB);    // 48: [T][3H] fused q|k|v
  bf16* ctx    = (bf16*)(w + 64 * MB);    // 16
  bf16* tmp1   = (bf16*)(w + 80 * MB);    // 16
  bf16* attn   = (bf16*)(w + 96 * MB);    // 16
  bf16* scores = (bf16*)(w + 112 * MB);   // 64 [112,176) live: qk->pv
  bf16* ff     = (bf16*)(w + 112 * MB);   // 48 [112,160) live: Wi->Wf (disjoint)
  bf16* tmp2   = (bf16*)(w + 176 * MB);   // 16
  bf16* vt     = (bf16*)(w + 192 * MB);   // 16
  bf16* Wqkvt  = (bf16*)(w + 208 * MB);   // 6: [3H][H] packed q|k|v rows
  bf16* Wot    = (bf16*)(w + 214 * MB);   // 2
  bf16* Wit    = (bf16*)(w + 216 * MB);   // 6
  bf16* Wft    = (bf16*)(w + 222 * MB);   // 6
  float* qkvb  = (float*)(w + 228 * MB);  // 12 KB
  float* out   = (float*)d_out;

  const float QSCALE = 0.08838834764831845f;  // 1/sqrt(128), applied in QK epilogue

  embed_ln_kernel<<<TT, 256, 0, stream>>>(x, pos, eg, ebeta, h);

  convert_w_kernel<<<dim3(HH / 32, HH / 32), 256, 0, stream>>>(Wq, Wqkvt, HH, HH);
  convert_w_kernel<<<dim3(HH / 32, HH / 32), 256, 0, stream>>>(Wk, Wqkvt + (size_t)HH * HH, HH, HH);
  convert_w_kernel<<<dim3(HH / 32, HH / 32), 256, 0, stream>>>(Wv, Wqkvt + (size_t)2 * HH * HH, HH, HH);
  convert_w_kernel<<<dim3(HH / 32, HH / 32), 256, 0, stream>>>(Wo, Wot, HH, HH);
  convert_w_kernel<<<dim3(FFF / 32, HH / 32), 256, 0, stream>>>(Wi, Wit, HH, FFF);
  convert_w_kernel<<<dim3(HH / 32, FFF / 32), 256, 0, stream>>>(Wf, Wft, FFF, HH);
  build_qkv_bias_kernel<<<12, 256, 0, stream>>>(qbias, vbias, qkvb);

  // fused QKV (V1): qkv[8192,3072] = h @ Wqkvt^T + qkvb
  mfma_gemm_kernel<0><<<dim3(24, 64, 1), 256, 0, stream>>>(
      h, HH, 0, 0, Wqkvt, HH, 0, 0, qkvb, qkv, 3 * HH, 0, 0, TT, 3 * HH, HH, 1.f);

  // scores[b,h,512,512] = (q_bh @ k_bh^T) * QSCALE  (k cols of qkv act as Bt)
  mfma_gemm_kernel<0><<<dim3(4, 4, BB * NHH), 256, 0, stream>>>(
      qkv, 3 * HH, (long long)SS * 3 * HH, HDD,
      qkv + HH, 3 * HH, (long long)SS * 3 * HH, HDD,
      nullptr,
      scores, SS, (long long)NHH * SS * SS, (long long)SS * SS,
      SS, SS, HDD, QSCALE);

  softmax_kernel<<<BB * NHH * SS / 4, 256, 0, stream>>>(scores);

  transpose_v_kernel<<<dim3(SS / 32, HDD / 32, BB * NHH), 256, 0, stream>>>(qkv + 2 * HH, vt);

  // ctx_bh[512,128] = probs_bh @ v_bh  (vt[dim][key] is Bt layout)
  mfma_gemm_kernel<0><<<dim3(1, 4, BB * NHH), 256, 0, stream>>>(
      scores, SS, (long long)NHH * SS * SS, (long long)SS * SS,
      vt, SS, (long long)NHH * HDD * SS, (long long)HDD * SS,
      nullptr,
      ctx, HH, (long long)SS * HH, HDD,
      SS, HDD, SS, 1.f);

  mfma_gemm_kernel<0><<<dim3(8, 64, 1), 256, 0, stream>>>(
      ctx, HH, 0, 0, Wot, HH, 0, 0, bo, tmp1, HH, 0, 0, TT, HH, HH, 1.f);
  add_ln_kernel<0><<<TT, 256, 0, stream>>>(tmp1, h, l1g, l1b, attn);

  // Wi (V2 dbuf A/B arm): identical shape to QKV (8192x3072x1024)
  gemm_dbuf_kernel<1><<<dim3(24, 64, 1), 256, 0, stream>>>(
      attn, HH, Wit, HH, bi, ff, FFF, TT, FFF, HH, 1.f);
  mfma_gemm_kernel<0><<<dim3(8, 64, 1), 256, 0, stream>>>(
      ff, FFF, 0, 0, Wft, FFF, 0, 0, bfb, tmp2, HH, 0, 0, TT, HH, FFF, 1.f);
  add_ln_kernel<1><<<TT, 256, 0, stream>>>(tmp2, attn, l2g, l2b, out);
}